// Round 2
// baseline (1039.529 us; speedup 1.0000x reference)
//
#include <hip/hip_runtime.h>
#include <cstdint>
#include <cstddef>

#define BN_EPS 1e-5

// ---------------- reductions (fp64 for exact sign decisions) ----------------

__global__ void zero_d(double* p, int n) {
  int i = blockIdx.x * blockDim.x + threadIdx.x;
  if (i < n) p[i] = 0.0;
}

// per-channel sum/sumsq over NCHW, grid (C, Y)
__global__ void reduce_nchw(const float* __restrict__ x, double* __restrict__ sums,
                            int C, int HW, int N) {
  int c = blockIdx.x;
  long total = (long)N * HW;
  double s = 0.0, s2 = 0.0;
  for (long i = (long)blockIdx.y * blockDim.x + threadIdx.x; i < total;
       i += (long)gridDim.y * blockDim.x) {
    long n = i / HW, hw = i - n * HW;
    double v = (double)x[(n * (long)C + c) * HW + hw];
    s += v; s2 += v * v;
  }
  for (int o = 32; o > 0; o >>= 1) {
    s  += __shfl_down(s, o, 64);
    s2 += __shfl_down(s2, o, 64);
  }
  __shared__ double ls[8], ls2[8];
  int lane = threadIdx.x & 63, w = threadIdx.x >> 6;
  if (lane == 0) { ls[w] = s; ls2[w] = s2; }
  __syncthreads();
  if (threadIdx.x == 0) {
    int nw = blockDim.x >> 6;
    double a = 0, b = 0;
    for (int i = 0; i < nw; i++) { a += ls[i]; b += ls2[i]; }
    atomicAdd(&sums[2 * c], a);
    atomicAdd(&sums[2 * c + 1], b);
  }
}

// per-feature sum/sumsq over rows of an R x F matrix
__global__ void reduce_cols(const float* __restrict__ x, double* __restrict__ sums,
                            int R, int F) {
  int f = blockIdx.x * blockDim.x + threadIdx.x;
  if (f >= F) return;
  double s = 0.0, s2 = 0.0;
  for (int r = 0; r < R; r++) {
    double v = (double)x[(long)r * F + f];
    s += v; s2 += v * v;
  }
  sums[2 * f] = s;
  sums[2 * f + 1] = s2;
}

__global__ void finalize_stats(const double* __restrict__ sums, double2* __restrict__ st,
                               int C, double cnt) {
  int c = blockIdx.x * blockDim.x + threadIdx.x;
  if (c >= C) return;
  double m = sums[2 * c] / cnt;
  double v = sums[2 * c + 1] / cnt - m * m;
  st[c] = make_double2(m, 1.0 / sqrt(v + BN_EPS));
}

// ---------------- sign / pack ----------------

// int8 signs for conv1 input (keeps exact 0 semantics)
__global__ void sign8_nchw(const float* __restrict__ x, const double2* __restrict__ st,
                           const float* __restrict__ g, const float* __restrict__ b,
                           int8_t* __restrict__ out, int C, int HW, long total) {
  long i = (long)blockIdx.x * blockDim.x + threadIdx.x;
  if (i >= total) return;
  int c = (int)((i / HW) % C);
  double2 s = st[c];
  float xn = (float)(((double)x[i] - s.x) * s.y) * g[c] + b[c];
  out[i] = xn > 0.f ? 1 : (xn < 0.f ? -1 : 0);
}

__global__ void sign8_flat(const float* __restrict__ w, int8_t* __restrict__ out, int n) {
  int i = blockIdx.x * blockDim.x + threadIdx.x;
  if (i >= n) return;
  float v = w[i];
  out[i] = v > 0.f ? 1 : (v < 0.f ? -1 : 0);
}

// pack BN-signed NCHW activations along channels: out [n][hw][W] (W = C/64)
// conv-layer BN means divide by non-pow2 counts -> exact zeros have ~0 probability;
// sign-only pack here (fc layers below carry a nonzero mask).
__global__ void pack_act(const float* __restrict__ x, const double2* __restrict__ st,
                         const float* __restrict__ g, const float* __restrict__ b,
                         uint64_t* __restrict__ out, int C, int HW, int N, int W) {
  long i = (long)blockIdx.x * blockDim.x + threadIdx.x;
  long total = (long)N * HW * W;
  if (i >= total) return;
  int w = (int)(i % W);
  long t = i / W;
  int hw = (int)(t % HW);
  int n = (int)(t / HW);
  uint64_t bits = 0;
  for (int k = 0; k < 64; k++) {
    int c = w * 64 + k;
    double2 s = st[c];
    float xn = (float)(((double)x[((long)n * C + c) * HW + hw] - s.x) * s.y) * g[c] + b[c];
    bits |= (uint64_t)(xn > 0.f) << k;
  }
  out[i] = bits;
}

// pack conv weights [co][ci][3][3] -> [co][tap][W]
__global__ void pack_wconv(const float* __restrict__ w, uint64_t* __restrict__ out,
                           int CO, int CI, int W) {
  int i = blockIdx.x * blockDim.x + threadIdx.x;
  int total = CO * 9 * W;
  if (i >= total) return;
  int wd = i % W;
  int t = i / W;
  int tap = t % 9, co = t / 9;
  uint64_t bits = 0;
  for (int k = 0; k < 64; k++) {
    int ci = wd * 64 + k;
    bits |= (uint64_t)(w[((long)co * CI + ci) * 9 + tap] > 0.f) << k;
  }
  out[i] = bits;
}

// pack BN-signed rows of R x F matrix -> [r][Wf][2] (sign word, nonzero word).
// BN1d means are exact lattice values (sum of quarter-ints / 128), so x == m
// (=> jnp.sign == 0) genuinely happens; zero features must contribute 0.
__global__ void pack_rows_nz(const float* __restrict__ x, const double2* __restrict__ st,
                             const float* __restrict__ g, const float* __restrict__ b,
                             uint64_t* __restrict__ out, int R, int F) {
  int Wf = F >> 6;
  int i = blockIdx.x * blockDim.x + threadIdx.x;
  if (i >= R * Wf) return;
  int w = i % Wf, r = i / Wf;
  uint64_t sbits = 0, nzbits = 0;
  for (int k = 0; k < 64; k++) {
    int f = w * 64 + k;
    double2 s = st[f];
    double d = (double)x[(long)r * F + f] - s.x;  // exact for lattice values
    float xn = (float)(d * s.y) * g[f] + b[f];
    sbits  |= (uint64_t)(xn > 0.f) << k;
    nzbits |= (uint64_t)(d != 0.0) << k;
  }
  out[2 * i]     = sbits;
  out[2 * i + 1] = nzbits;
}

// pack fc weights [O][F] -> [o][F/64]  (gaussian weights: never exactly 0)
__global__ void pack_wfc(const float* __restrict__ w, uint64_t* __restrict__ out,
                         int O, int F) {
  int Wf = F >> 6;
  int i = blockIdx.x * blockDim.x + threadIdx.x;
  if (i >= O * Wf) return;
  int wd = i % Wf, o = i / Wf;
  uint64_t bits = 0;
  for (int k = 0; k < 64; k++)
    bits |= (uint64_t)(w[(long)o * F + wd * 64 + k] > 0.f) << k;
  out[i] = bits;
}

// ---------------- fused conv + maxpool + prelu ----------------

// conv1: Cin=3 scalar int8 path. s0 [n][3][64][64], wsgn [co][3][3][3], out [n][128][31][31]
__global__ void conv1_pool(const int8_t* __restrict__ s0, const int8_t* __restrict__ wsgn,
                           const float* __restrict__ cp, float* __restrict__ out) {
  __shared__ int wl[3][3][3];
  int co = blockIdx.y, n = blockIdx.z;
  if (threadIdx.x < 27) {
    int t = threadIdx.x;
    wl[t / 9][(t % 9) / 3][t % 3] = wsgn[co * 27 + t];
  }
  __syncthreads();
  int p = blockIdx.x * blockDim.x + threadIdx.x;
  if (p >= 31 * 31) return;
  int py = p / 31, px = p % 31;
  int acc[2][2] = {{0, 0}, {0, 0}};
  for (int ci = 0; ci < 3; ci++) {
    int v[4][4];
    const int8_t* base = s0 + (((long)n * 3 + ci) * 64 + 2 * py) * 64 + 2 * px;
#pragma unroll
    for (int iy = 0; iy < 4; iy++)
#pragma unroll
      for (int ix = 0; ix < 4; ix++)
        v[iy][ix] = (int)base[iy * 64 + ix];
#pragma unroll
    for (int dy = 0; dy < 2; dy++)
#pragma unroll
      for (int dx = 0; dx < 2; dx++) {
        int a = 0;
#pragma unroll
        for (int ky = 0; ky < 3; ky++)
#pragma unroll
          for (int kx = 0; kx < 3; kx++)
            a += v[ky + dy][kx + dx] * wl[ci][ky][kx];
        acc[dy][dx] += a;
      }
  }
  int m = max(max(acc[0][0], acc[0][1]), max(acc[1][0], acc[1][1]));
  float f = (float)m;
  float alpha = cp[0];
  out[(((long)n * 128 + co) * 31 + py) * 31 + px] = m >= 0 ? f : alpha * f;
}

// xnor-popcount conv + pool + prelu. in [n][IH][IH][W], wt [co][9][W], out [n][CO][PH][PH]
template <int W>
__global__ void convp_pool(const uint64_t* __restrict__ in, const uint64_t* __restrict__ wt,
                           const float* __restrict__ cp, float* __restrict__ out,
                           int IH, int PH, int CO) {
  __shared__ uint64_t wl[9 * W];
  int co = blockIdx.y, n = blockIdx.z;
  for (int i = threadIdx.x; i < 9 * W; i += blockDim.x) wl[i] = wt[(long)co * 9 * W + i];
  __syncthreads();
  int p = blockIdx.x * blockDim.x + threadIdx.x;
  if (p >= PH * PH) return;
  int py = p / PH, px = p % PH;
  uint64_t patch[4][4][W];
  const uint64_t* base = in + (((long)n * IH + 2 * py) * IH + 2 * px) * W;
#pragma unroll
  for (int iy = 0; iy < 4; iy++)
#pragma unroll
    for (int ix = 0; ix < 4; ix++)
#pragma unroll
      for (int wd = 0; wd < W; wd++)
        patch[iy][ix][wd] = base[((long)iy * IH + ix) * W + wd];
  int best = -0x7FFFFFFF;
#pragma unroll
  for (int dy = 0; dy < 2; dy++)
#pragma unroll
    for (int dx = 0; dx < 2; dx++) {
      int pc = 0;
#pragma unroll
      for (int ky = 0; ky < 3; ky++)
#pragma unroll
        for (int kx = 0; kx < 3; kx++)
#pragma unroll
          for (int wd = 0; wd < W; wd++)
            pc += __popcll(patch[ky + dy][kx + dx][wd] ^ wl[(ky * 3 + kx) * W + wd]);
      int dot = 9 * 64 * W - 2 * pc;
      best = max(best, dot);
    }
  float f = (float)best;
  float alpha = cp[0];
  out[(((long)n * CO + co) * PH + py) * PH + px] = best >= 0 ? f : alpha * f;
}

// ---------------- binary fc (with nonzero mask on activations) ----------------

// xp [r][Wf][2], wp [o][Wf], out [r][O] with prelu.  grid (O/256, R)
__global__ void fc_bin(const uint64_t* __restrict__ xp, const uint64_t* __restrict__ wp,
                       const float* __restrict__ cp, float* __restrict__ out,
                       int O, int Wf) {
  __shared__ uint64_t xs[288], xz[288];
  int r = blockIdx.y;
  for (int i = threadIdx.x; i < Wf; i += blockDim.x) {
    xs[i] = xp[((long)r * Wf + i) * 2];
    xz[i] = xp[((long)r * Wf + i) * 2 + 1];
  }
  __syncthreads();
  int o = blockIdx.x * blockDim.x + threadIdx.x;
  if (o >= O) return;
  int pc = 0, nzc = 0;
  const uint64_t* wr = wp + (long)o * Wf;
  for (int wd = 0; wd < Wf; wd++) {
    uint64_t nz = xz[wd];
    pc  += __popcll((xs[wd] ^ wr[wd]) & nz);
    nzc += __popcll(nz);
  }
  int dot = nzc - 2 * pc;
  float f = (float)dot;
  float alpha = cp[0];
  out[(long)r * O + o] = dot >= 0 ? f : alpha * f;
}

// final fc + prelu + scale -> d_out
__global__ void fc_bin_scale(const uint64_t* __restrict__ xp, const uint64_t* __restrict__ wp,
                             const float* __restrict__ cp, const float* __restrict__ scale,
                             float* __restrict__ out, int R, int O, int Wf) {
  int i = blockIdx.x * blockDim.x + threadIdx.x;
  if (i >= R * O) return;
  int o = i % O, r = i / O;
  int pc = 0, nzc = 0;
  for (int wd = 0; wd < Wf; wd++) {
    uint64_t nz = xp[((long)r * Wf + wd) * 2 + 1];
    pc  += __popcll((xp[((long)r * Wf + wd) * 2] ^ wp[(long)o * Wf + wd]) & nz);
    nzc += __popcll(nz);
  }
  int dot = nzc - 2 * pc;
  float f = (float)dot;
  float alpha = cp[0];
  f = dot >= 0 ? f : alpha * f;
  out[i] = f * scale[0];
}

// ---------------- launch ----------------

extern "C" void kernel_launch(void* const* d_in, const int* in_sizes, int n_in,
                              void* d_out, int out_size, void* d_ws, size_t ws_size,
                              hipStream_t stream) {
  const float* x   = (const float*)d_in[0];
  const float* cg0 = (const float*)d_in[1];
  const float* cb0 = (const float*)d_in[2];
  const float* cw0 = (const float*)d_in[3];
  const float* cp0 = (const float*)d_in[4];
  const float* cg1 = (const float*)d_in[5];
  const float* cb1 = (const float*)d_in[6];
  const float* cw1 = (const float*)d_in[7];
  const float* cp1 = (const float*)d_in[8];
  const float* cg2 = (const float*)d_in[9];
  const float* cb2 = (const float*)d_in[10];
  const float* cw2 = (const float*)d_in[11];
  const float* cp2 = (const float*)d_in[12];
  const float* fg0 = (const float*)d_in[13];
  const float* fb0 = (const float*)d_in[14];
  const float* fw0 = (const float*)d_in[15];
  const float* fp0 = (const float*)d_in[16];
  const float* fg1 = (const float*)d_in[17];
  const float* fb1 = (const float*)d_in[18];
  const float* fw1 = (const float*)d_in[19];
  const float* fp1 = (const float*)d_in[20];
  const float* scl = (const float*)d_in[21];

  char* ws = (char*)d_ws;
  size_t off = 0;
  auto alloc = [&](size_t bytes) {
    size_t r = off;
    off += (bytes + 255) & ~(size_t)255;
    return r;
  };
  // channel-region offsets inside sums/stats (channel units): 3,128,256,18432,1024
  const int C0_OFF = 0, C1_OFF = 16, C2_OFF = 160, C3_OFF = 448, C4_OFF = 18944;
  const int NCH = 19968;

  double*   sums  = (double*)(ws + alloc((size_t)NCH * 2 * sizeof(double)));
  double2*  stats = (double2*)(ws + alloc((size_t)NCH * sizeof(double2)));
  int8_t*   s0    = (int8_t*)(ws + alloc(128L * 3 * 64 * 64));
  int8_t*   ws1   = (int8_t*)(ws + alloc(128L * 27));
  float*    a1    = (float*)(ws + alloc(128L * 128 * 31 * 31 * 4));
  uint64_t* s1p   = (uint64_t*)(ws + alloc(128L * 31 * 31 * 2 * 8));
  uint64_t* w1p   = (uint64_t*)(ws + alloc(256L * 9 * 2 * 8));
  float*    a2    = (float*)(ws + alloc(128L * 256 * 14 * 14 * 4));
  uint64_t* s2p   = (uint64_t*)(ws + alloc(128L * 14 * 14 * 4 * 8));
  uint64_t* w2p   = (uint64_t*)(ws + alloc(512L * 9 * 4 * 8));
  float*    a3    = (float*)(ws + alloc(128L * 512 * 36 * 4));
  uint64_t* s3p   = (uint64_t*)(ws + alloc(128L * 288 * 2 * 8));
  uint64_t* w3p   = (uint64_t*)(ws + alloc(1024L * 288 * 8));
  float*    f1    = (float*)(ws + alloc(128L * 1024 * 4));
  uint64_t* s4p   = (uint64_t*)(ws + alloc(128L * 16 * 2 * 8));
  uint64_t* w4p   = (uint64_t*)(ws + alloc(10L * 16 * 8));

  const int B = 256;

  // 0) zero all reduction accumulators
  zero_d<<<dim3((NCH * 2 + B - 1) / B), B, 0, stream>>>(sums, NCH * 2);

  // ---- block 0: BN(x) -> sign -> conv1 -> pool -> prelu ----
  reduce_nchw<<<dim3(3, 256), B, 0, stream>>>(x, sums + 2 * C0_OFF, 3, 4096, 128);
  finalize_stats<<<1, 64, 0, stream>>>(sums + 2 * C0_OFF, stats + C0_OFF, 3, 524288.0);
  {
    long total = 128L * 3 * 4096;
    sign8_nchw<<<dim3((unsigned)((total + B - 1) / B)), B, 0, stream>>>(
        x, stats + C0_OFF, cg0, cb0, s0, 3, 4096, total);
  }
  sign8_flat<<<dim3((3456 + B - 1) / B), B, 0, stream>>>(cw0, ws1, 3456);
  conv1_pool<<<dim3(4, 128, 128), B, 0, stream>>>(s0, ws1, cp0, a1);

  // ---- block 1: BN(a1) -> pack -> conv2 -> pool -> prelu ----
  reduce_nchw<<<dim3(128, 16), B, 0, stream>>>(a1, sums + 2 * C1_OFF, 128, 961, 128);
  finalize_stats<<<1, 128, 0, stream>>>(sums + 2 * C1_OFF, stats + C1_OFF, 128, 123008.0);
  {
    long total = 128L * 961 * 2;
    pack_act<<<dim3((unsigned)((total + B - 1) / B)), B, 0, stream>>>(
        a1, stats + C1_OFF, cg1, cb1, s1p, 128, 961, 128, 2);
  }
  pack_wconv<<<dim3((256 * 9 * 2 + B - 1) / B), B, 0, stream>>>(cw1, w1p, 256, 128, 2);
  convp_pool<2><<<dim3(1, 256, 128), B, 0, stream>>>(s1p, w1p, cp1, a2, 31, 14, 256);

  // ---- block 2: BN(a2) -> pack -> conv3 -> pool -> prelu ----
  reduce_nchw<<<dim3(256, 8), B, 0, stream>>>(a2, sums + 2 * C2_OFF, 256, 196, 128);
  finalize_stats<<<1, 256, 0, stream>>>(sums + 2 * C2_OFF, stats + C2_OFF, 256, 25088.0);
  {
    long total = 128L * 196 * 4;
    pack_act<<<dim3((unsigned)((total + B - 1) / B)), B, 0, stream>>>(
        a2, stats + C2_OFF, cg2, cb2, s2p, 256, 196, 128, 4);
  }
  pack_wconv<<<dim3((512 * 9 * 4 + B - 1) / B), B, 0, stream>>>(cw2, w2p, 512, 256, 4);
  convp_pool<4><<<dim3(1, 512, 128), 64, 0, stream>>>(s2p, w2p, cp2, a3, 14, 6, 512);

  // ---- fc 0: BN1d -> sign @ sign(W).T -> prelu ----
  reduce_cols<<<dim3((18432 + B - 1) / B), B, 0, stream>>>(a3, sums + 2 * C3_OFF, 128, 18432);
  finalize_stats<<<dim3((18432 + B - 1) / B), B, 0, stream>>>(sums + 2 * C3_OFF, stats + C3_OFF,
                                                             18432, 128.0);
  pack_rows_nz<<<dim3((128 * 288 + B - 1) / B), B, 0, stream>>>(a3, stats + C3_OFF, fg0, fb0,
                                                                s3p, 128, 18432);
  pack_wfc<<<dim3((1024 * 288 + B - 1) / B), B, 0, stream>>>(fw0, w3p, 1024, 18432);
  fc_bin<<<dim3(4, 128), B, 0, stream>>>(s3p, w3p, fp0, f1, 1024, 288);

  // ---- fc 1: BN1d -> sign @ sign(W).T -> prelu -> scale ----
  reduce_cols<<<dim3((1024 + B - 1) / B), B, 0, stream>>>(f1, sums + 2 * C4_OFF, 128, 1024);
  finalize_stats<<<dim3(4), B, 0, stream>>>(sums + 2 * C4_OFF, stats + C4_OFF, 1024, 128.0);
  pack_rows_nz<<<dim3((128 * 16 + B - 1) / B), B, 0, stream>>>(f1, stats + C4_OFF, fg1, fb1,
                                                               s4p, 128, 1024);
  pack_wfc<<<dim3(1, 1, 1), B, 0, stream>>>(fw1, w4p, 10, 1024);
  fc_bin_scale<<<dim3(5), B, 0, stream>>>(s4p, w4p, fp1, scl, (float*)d_out, 128, 10, 16);
}

// Round 3
// 712.439 us; speedup vs baseline: 1.4591x; 1.4591x over previous
//
#include <hip/hip_runtime.h>
#include <cstdint>
#include <cstddef>

#define BN_EPS 1e-5

// ---------------- reductions (fp64 for exact sign decisions) ----------------

__global__ void zero_d(double* p, int n) {
  int i = blockIdx.x * blockDim.x + threadIdx.x;
  if (i < n) p[i] = 0.0;
}

// per-channel sum/sumsq over NCHW, grid (C, Y)
__global__ void reduce_nchw(const float* __restrict__ x, double* __restrict__ sums,
                            int C, int HW, int N) {
  int c = blockIdx.x;
  long total = (long)N * HW;
  double s = 0.0, s2 = 0.0;
  for (long i = (long)blockIdx.y * blockDim.x + threadIdx.x; i < total;
       i += (long)gridDim.y * blockDim.x) {
    long n = i / HW, hw = i - n * HW;
    double v = (double)x[(n * (long)C + c) * HW + hw];
    s += v; s2 += v * v;
  }
  for (int o = 32; o > 0; o >>= 1) {
    s  += __shfl_down(s, o, 64);
    s2 += __shfl_down(s2, o, 64);
  }
  __shared__ double ls[8], ls2[8];
  int lane = threadIdx.x & 63, w = threadIdx.x >> 6;
  if (lane == 0) { ls[w] = s; ls2[w] = s2; }
  __syncthreads();
  if (threadIdx.x == 0) {
    int nw = blockDim.x >> 6;
    double a = 0, b = 0;
    for (int i = 0; i < nw; i++) { a += ls[i]; b += ls2[i]; }
    atomicAdd(&sums[2 * c], a);
    atomicAdd(&sums[2 * c + 1], b);
  }
}

// per-feature sum/sumsq over rows of an R x F matrix
__global__ void reduce_cols(const float* __restrict__ x, double* __restrict__ sums,
                            int R, int F) {
  int f = blockIdx.x * blockDim.x + threadIdx.x;
  if (f >= F) return;
  double s = 0.0, s2 = 0.0;
  for (int r = 0; r < R; r++) {
    double v = (double)x[(long)r * F + f];
    s += v; s2 += v * v;
  }
  sums[2 * f] = s;
  sums[2 * f + 1] = s2;
}

__global__ void finalize_stats(const double* __restrict__ sums, double2* __restrict__ st,
                               int C, double cnt) {
  int c = blockIdx.x * blockDim.x + threadIdx.x;
  if (c >= C) return;
  double m = sums[2 * c] / cnt;
  double v = sums[2 * c + 1] / cnt - m * m;
  st[c] = make_double2(m, 1.0 / sqrt(v + BN_EPS));
}

// ---------------- sign / pack ----------------

__global__ void sign8_nchw(const float* __restrict__ x, const double2* __restrict__ st,
                           const float* __restrict__ g, const float* __restrict__ b,
                           int8_t* __restrict__ out, int C, int HW, long total) {
  long i = (long)blockIdx.x * blockDim.x + threadIdx.x;
  if (i >= total) return;
  int c = (int)((i / HW) % C);
  double2 s = st[c];
  float xn = (float)(((double)x[i] - s.x) * s.y) * g[c] + b[c];
  out[i] = xn > 0.f ? 1 : (xn < 0.f ? -1 : 0);
}

__global__ void sign8_flat(const float* __restrict__ w, int8_t* __restrict__ out, int n) {
  int i = blockIdx.x * blockDim.x + threadIdx.x;
  if (i >= n) return;
  float v = w[i];
  out[i] = v > 0.f ? 1 : (v < 0.f ? -1 : 0);
}

// pack BN-signed NCHW activations along channels: out [n][hw][W] (W = C/64)
__global__ void pack_act(const float* __restrict__ x, const double2* __restrict__ st,
                         const float* __restrict__ g, const float* __restrict__ b,
                         uint64_t* __restrict__ out, int C, int HW, int N, int W) {
  long i = (long)blockIdx.x * blockDim.x + threadIdx.x;
  long total = (long)N * HW * W;
  if (i >= total) return;
  int w = (int)(i % W);
  long t = i / W;
  int hw = (int)(t % HW);
  int n = (int)(t / HW);
  uint64_t bits = 0;
  for (int k = 0; k < 64; k++) {
    int c = w * 64 + k;
    double2 s = st[c];
    float xn = (float)(((double)x[((long)n * C + c) * HW + hw] - s.x) * s.y) * g[c] + b[c];
    bits |= (uint64_t)(xn > 0.f) << k;
  }
  out[i] = bits;
}

// pack conv weights [co][ci][3][3] -> [co][tap][W]
__global__ void pack_wconv(const float* __restrict__ w, uint64_t* __restrict__ out,
                           int CO, int CI, int W) {
  int i = blockIdx.x * blockDim.x + threadIdx.x;
  int total = CO * 9 * W;
  if (i >= total) return;
  int wd = i % W;
  int t = i / W;
  int tap = t % 9, co = t / 9;
  uint64_t bits = 0;
  for (int k = 0; k < 64; k++) {
    int ci = wd * 64 + k;
    bits |= (uint64_t)(w[((long)co * CI + ci) * 9 + tap] > 0.f) << k;
  }
  out[i] = bits;
}

// pack BN-signed rows of R x F matrix -> [r][Wf][2] (sign word, nonzero word)
__global__ void pack_rows_nz(const float* __restrict__ x, const double2* __restrict__ st,
                             const float* __restrict__ g, const float* __restrict__ b,
                             uint64_t* __restrict__ out, int R, int F) {
  int Wf = F >> 6;
  int i = blockIdx.x * blockDim.x + threadIdx.x;
  if (i >= R * Wf) return;
  int w = i % Wf, r = i / Wf;
  uint64_t sbits = 0, nzbits = 0;
  for (int k = 0; k < 64; k++) {
    int f = w * 64 + k;
    double2 s = st[f];
    double d = (double)x[(long)r * F + f] - s.x;  // exact for lattice values
    float xn = (float)(d * s.y) * g[f] + b[f];
    sbits  |= (uint64_t)(xn > 0.f) << k;
    nzbits |= (uint64_t)(d != 0.0) << k;
  }
  out[2 * i]     = sbits;
  out[2 * i + 1] = nzbits;
}

// pack fc weights [O][F] -> [o][F/64]  (gaussian weights: never exactly 0)
__global__ void pack_wfc(const float* __restrict__ w, uint64_t* __restrict__ out,
                         int O, int F) {
  int Wf = F >> 6;
  int i = blockIdx.x * blockDim.x + threadIdx.x;
  if (i >= O * Wf) return;
  int wd = i % Wf, o = i / Wf;
  uint64_t bits = 0;
  for (int k = 0; k < 64; k++)
    bits |= (uint64_t)(w[(long)o * F + wd * 64 + k] > 0.f) << k;
  out[i] = bits;
}

// ---------------- fused conv + maxpool + prelu ----------------

// conv1: Cin=3 scalar int8 path. s0 [n][3][64][64], wsgn [co][3][3][3], out [n][128][31][31]
__global__ void conv1_pool(const int8_t* __restrict__ s0, const int8_t* __restrict__ wsgn,
                           const float* __restrict__ cp, float* __restrict__ out) {
  __shared__ int wl[3][3][3];
  int co = blockIdx.y, n = blockIdx.z;
  if (threadIdx.x < 27) {
    int t = threadIdx.x;
    wl[t / 9][(t % 9) / 3][t % 3] = wsgn[co * 27 + t];
  }
  __syncthreads();
  int p = blockIdx.x * blockDim.x + threadIdx.x;
  if (p >= 31 * 31) return;
  int py = p / 31, px = p % 31;
  int acc[2][2] = {{0, 0}, {0, 0}};
  for (int ci = 0; ci < 3; ci++) {
    int v[4][4];
    const int8_t* base = s0 + (((long)n * 3 + ci) * 64 + 2 * py) * 64 + 2 * px;
#pragma unroll
    for (int iy = 0; iy < 4; iy++)
#pragma unroll
      for (int ix = 0; ix < 4; ix++)
        v[iy][ix] = (int)base[iy * 64 + ix];
#pragma unroll
    for (int dy = 0; dy < 2; dy++)
#pragma unroll
      for (int dx = 0; dx < 2; dx++) {
        int a = 0;
#pragma unroll
        for (int ky = 0; ky < 3; ky++)
#pragma unroll
          for (int kx = 0; kx < 3; kx++)
            a += v[ky + dy][kx + dx] * wl[ci][ky][kx];
        acc[dy][dx] += a;
      }
  }
  int m = max(max(acc[0][0], acc[0][1]), max(acc[1][0], acc[1][1]));
  float f = (float)m;
  float alpha = cp[0];
  out[(((long)n * 128 + co) * 31 + py) * 31 + px] = m >= 0 ? f : alpha * f;
}

// xnor-popcount conv + pool + prelu, v2: LDS-staged, no per-thread arrays (the
// v1 patch[4][4][W] array was demoted to scratch -> 1.16 GB/dispatch spill traffic).
// in [n][IH][IH][W], wt [co][9][W], out [n][CO][PH][PH].
// Block: 256 threads = 64 co (lanes) x 4 position slots (waves). Patch reads are
// wave-uniform LDS broadcasts; weight rows padded to 9W+1 to stagger banks.
template <int W, int IH, int PH, int POSCH>
__global__ __launch_bounds__(256) void convp_pool2(
    const uint64_t* __restrict__ in, const uint64_t* __restrict__ wt,
    const float* __restrict__ cp, float* __restrict__ out, int CO) {
  constexpr int PS = 9 * W + 1;
  __shared__ uint64_t sIn[IH * IH * W];
  __shared__ uint64_t sW[64 * PS];
  int n = blockIdx.y;
  int cg = blockIdx.x / POSCH;
  int chunk = blockIdx.x % POSCH;
  int t = threadIdx.x;
  const uint64_t* src = in + (long)n * (IH * IH * W);
  for (int i = t; i < IH * IH * W; i += 256) sIn[i] = src[i];
  int cobase = cg * 64;
  for (int i = t; i < 64 * 9 * W; i += 256) {
    int col = i / (9 * W), r = i - col * (9 * W);
    sW[col * PS + r] = wt[((long)(cobase + col)) * (9 * W) + r];
  }
  __syncthreads();
  int co_l = t & 63;
  int slot = t >> 6;  // wave id: all 64 lanes of a wave share one position
  float alpha = cp[0];
  int co = cobase + co_l;
  const uint64_t* wrow = &sW[co_l * PS];
  for (int pos = chunk * 4 + slot; pos < PH * PH; pos += POSCH * 4) {
    int py = pos / PH, px = pos % PH;
    int pc00 = 0, pc01 = 0, pc10 = 0, pc11 = 0;
#pragma unroll
    for (int ky = 0; ky < 3; ky++) {
#pragma unroll
      for (int kx = 0; kx < 3; kx++) {
        uint64_t wv[W];
#pragma unroll
        for (int wd = 0; wd < W; wd++) wv[wd] = wrow[(ky * 3 + kx) * W + wd];
        {
          const uint64_t* pr = &sIn[((2 * py + ky) * IH + (2 * px + kx)) * W];
          int p = 0;
#pragma unroll
          for (int wd = 0; wd < W; wd++) p += __popcll(pr[wd] ^ wv[wd]);
          pc00 += p;
        }
        {
          const uint64_t* pr = &sIn[((2 * py + ky) * IH + (2 * px + 1 + kx)) * W];
          int p = 0;
#pragma unroll
          for (int wd = 0; wd < W; wd++) p += __popcll(pr[wd] ^ wv[wd]);
          pc01 += p;
        }
        {
          const uint64_t* pr = &sIn[((2 * py + 1 + ky) * IH + (2 * px + kx)) * W];
          int p = 0;
#pragma unroll
          for (int wd = 0; wd < W; wd++) p += __popcll(pr[wd] ^ wv[wd]);
          pc10 += p;
        }
        {
          const uint64_t* pr = &sIn[((2 * py + 1 + ky) * IH + (2 * px + 1 + kx)) * W];
          int p = 0;
#pragma unroll
          for (int wd = 0; wd < W; wd++) p += __popcll(pr[wd] ^ wv[wd]);
          pc11 += p;
        }
      }
    }
    const int K = 9 * 64 * W;
    int d00 = K - 2 * pc00, d01 = K - 2 * pc01, d10 = K - 2 * pc10, d11 = K - 2 * pc11;
    int best = max(max(d00, d01), max(d10, d11));
    float f = (float)best;
    out[(((long)n * CO + co) * PH + py) * PH + px] = best >= 0 ? f : alpha * f;
  }
}

// ---------------- binary fc (with nonzero mask on activations) ----------------

__global__ void fc_bin(const uint64_t* __restrict__ xp, const uint64_t* __restrict__ wp,
                       const float* __restrict__ cp, float* __restrict__ out,
                       int O, int Wf) {
  __shared__ uint64_t xs[288], xz[288];
  int r = blockIdx.y;
  for (int i = threadIdx.x; i < Wf; i += blockDim.x) {
    xs[i] = xp[((long)r * Wf + i) * 2];
    xz[i] = xp[((long)r * Wf + i) * 2 + 1];
  }
  __syncthreads();
  int o = blockIdx.x * blockDim.x + threadIdx.x;
  if (o >= O) return;
  int pc = 0, nzc = 0;
  const uint64_t* wr = wp + (long)o * Wf;
  for (int wd = 0; wd < Wf; wd++) {
    uint64_t nz = xz[wd];
    pc  += __popcll((xs[wd] ^ wr[wd]) & nz);
    nzc += __popcll(nz);
  }
  int dot = nzc - 2 * pc;
  float f = (float)dot;
  float alpha = cp[0];
  out[(long)r * O + o] = dot >= 0 ? f : alpha * f;
}

__global__ void fc_bin_scale(const uint64_t* __restrict__ xp, const uint64_t* __restrict__ wp,
                             const float* __restrict__ cp, const float* __restrict__ scale,
                             float* __restrict__ out, int R, int O, int Wf) {
  int i = blockIdx.x * blockDim.x + threadIdx.x;
  if (i >= R * O) return;
  int o = i % O, r = i / O;
  int pc = 0, nzc = 0;
  for (int wd = 0; wd < Wf; wd++) {
    uint64_t nz = xp[((long)r * Wf + wd) * 2 + 1];
    pc  += __popcll((xp[((long)r * Wf + wd) * 2] ^ wp[(long)o * Wf + wd]) & nz);
    nzc += __popcll(nz);
  }
  int dot = nzc - 2 * pc;
  float f = (float)dot;
  float alpha = cp[0];
  f = dot >= 0 ? f : alpha * f;
  out[i] = f * scale[0];
}

// ---------------- launch ----------------

extern "C" void kernel_launch(void* const* d_in, const int* in_sizes, int n_in,
                              void* d_out, int out_size, void* d_ws, size_t ws_size,
                              hipStream_t stream) {
  const float* x   = (const float*)d_in[0];
  const float* cg0 = (const float*)d_in[1];
  const float* cb0 = (const float*)d_in[2];
  const float* cw0 = (const float*)d_in[3];
  const float* cp0 = (const float*)d_in[4];
  const float* cg1 = (const float*)d_in[5];
  const float* cb1 = (const float*)d_in[6];
  const float* cw1 = (const float*)d_in[7];
  const float* cp1 = (const float*)d_in[8];
  const float* cg2 = (const float*)d_in[9];
  const float* cb2 = (const float*)d_in[10];
  const float* cw2 = (const float*)d_in[11];
  const float* cp2 = (const float*)d_in[12];
  const float* fg0 = (const float*)d_in[13];
  const float* fb0 = (const float*)d_in[14];
  const float* fw0 = (const float*)d_in[15];
  const float* fp0 = (const float*)d_in[16];
  const float* fg1 = (const float*)d_in[17];
  const float* fb1 = (const float*)d_in[18];
  const float* fw1 = (const float*)d_in[19];
  const float* fp1 = (const float*)d_in[20];
  const float* scl = (const float*)d_in[21];

  char* ws = (char*)d_ws;
  size_t off = 0;
  auto alloc = [&](size_t bytes) {
    size_t r = off;
    off += (bytes + 255) & ~(size_t)255;
    return r;
  };
  const int C0_OFF = 0, C1_OFF = 16, C2_OFF = 160, C3_OFF = 448, C4_OFF = 18944;
  const int NCH = 19968;

  double*   sums  = (double*)(ws + alloc((size_t)NCH * 2 * sizeof(double)));
  double2*  stats = (double2*)(ws + alloc((size_t)NCH * sizeof(double2)));
  int8_t*   s0    = (int8_t*)(ws + alloc(128L * 3 * 64 * 64));
  int8_t*   ws1   = (int8_t*)(ws + alloc(128L * 27));
  float*    a1    = (float*)(ws + alloc(128L * 128 * 31 * 31 * 4));
  uint64_t* s1p   = (uint64_t*)(ws + alloc(128L * 31 * 31 * 2 * 8));
  uint64_t* w1p   = (uint64_t*)(ws + alloc(256L * 9 * 2 * 8));
  float*    a2    = (float*)(ws + alloc(128L * 256 * 14 * 14 * 4));
  uint64_t* s2p   = (uint64_t*)(ws + alloc(128L * 14 * 14 * 4 * 8));
  uint64_t* w2p   = (uint64_t*)(ws + alloc(512L * 9 * 4 * 8));
  float*    a3    = (float*)(ws + alloc(128L * 512 * 36 * 4));
  uint64_t* s3p   = (uint64_t*)(ws + alloc(128L * 288 * 2 * 8));
  uint64_t* w3p   = (uint64_t*)(ws + alloc(1024L * 288 * 8));
  float*    f1    = (float*)(ws + alloc(128L * 1024 * 4));
  uint64_t* s4p   = (uint64_t*)(ws + alloc(128L * 16 * 2 * 8));
  uint64_t* w4p   = (uint64_t*)(ws + alloc(10L * 16 * 8));

  const int B = 256;

  zero_d<<<dim3((NCH * 2 + B - 1) / B), B, 0, stream>>>(sums, NCH * 2);

  // ---- block 0: BN(x) -> sign -> conv1 -> pool -> prelu ----
  reduce_nchw<<<dim3(3, 256), B, 0, stream>>>(x, sums + 2 * C0_OFF, 3, 4096, 128);
  finalize_stats<<<1, 64, 0, stream>>>(sums + 2 * C0_OFF, stats + C0_OFF, 3, 524288.0);
  {
    long total = 128L * 3 * 4096;
    sign8_nchw<<<dim3((unsigned)((total + B - 1) / B)), B, 0, stream>>>(
        x, stats + C0_OFF, cg0, cb0, s0, 3, 4096, total);
  }
  sign8_flat<<<dim3((3456 + B - 1) / B), B, 0, stream>>>(cw0, ws1, 3456);
  conv1_pool<<<dim3(4, 128, 128), B, 0, stream>>>(s0, ws1, cp0, a1);

  // ---- block 1: BN(a1) -> pack -> conv2 -> pool -> prelu ----
  reduce_nchw<<<dim3(128, 16), B, 0, stream>>>(a1, sums + 2 * C1_OFF, 128, 961, 128);
  finalize_stats<<<1, 128, 0, stream>>>(sums + 2 * C1_OFF, stats + C1_OFF, 128, 123008.0);
  {
    long total = 128L * 961 * 2;
    pack_act<<<dim3((unsigned)((total + B - 1) / B)), B, 0, stream>>>(
        a1, stats + C1_OFF, cg1, cb1, s1p, 128, 961, 128, 2);
  }
  pack_wconv<<<dim3((256 * 9 * 2 + B - 1) / B), B, 0, stream>>>(cw1, w1p, 256, 128, 2);
  // 4 co-groups x 4 pos-chunks
  convp_pool2<2, 31, 14, 4><<<dim3(16, 128), 256, 0, stream>>>(s1p, w1p, cp1, a2, 256);

  // ---- block 2: BN(a2) -> pack -> conv3 -> pool -> prelu ----
  reduce_nchw<<<dim3(256, 8), B, 0, stream>>>(a2, sums + 2 * C2_OFF, 256, 196, 128);
  finalize_stats<<<1, 256, 0, stream>>>(sums + 2 * C2_OFF, stats + C2_OFF, 256, 25088.0);
  {
    long total = 128L * 196 * 4;
    pack_act<<<dim3((unsigned)((total + B - 1) / B)), B, 0, stream>>>(
        a2, stats + C2_OFF, cg2, cb2, s2p, 256, 196, 128, 4);
  }
  pack_wconv<<<dim3((512 * 9 * 4 + B - 1) / B), B, 0, stream>>>(cw2, w2p, 512, 256, 4);
  // 8 co-groups x 2 pos-chunks
  convp_pool2<4, 14, 6, 2><<<dim3(16, 128), 256, 0, stream>>>(s2p, w2p, cp2, a3, 512);

  // ---- fc 0: BN1d -> sign @ sign(W).T -> prelu ----
  reduce_cols<<<dim3((18432 + B - 1) / B), B, 0, stream>>>(a3, sums + 2 * C3_OFF, 128, 18432);
  finalize_stats<<<dim3((18432 + B - 1) / B), B, 0, stream>>>(sums + 2 * C3_OFF, stats + C3_OFF,
                                                             18432, 128.0);
  pack_rows_nz<<<dim3((128 * 288 + B - 1) / B), B, 0, stream>>>(a3, stats + C3_OFF, fg0, fb0,
                                                                s3p, 128, 18432);
  pack_wfc<<<dim3((1024 * 288 + B - 1) / B), B, 0, stream>>>(fw0, w3p, 1024, 18432);
  fc_bin<<<dim3(4, 128), B, 0, stream>>>(s3p, w3p, fp0, f1, 1024, 288);

  // ---- fc 1: BN1d -> sign @ sign(W).T -> prelu -> scale ----
  reduce_cols<<<dim3((1024 + B - 1) / B), B, 0, stream>>>(f1, sums + 2 * C4_OFF, 128, 1024);
  finalize_stats<<<dim3(4), B, 0, stream>>>(sums + 2 * C4_OFF, stats + C4_OFF, 1024, 128.0);
  pack_rows_nz<<<dim3((128 * 16 + B - 1) / B), B, 0, stream>>>(f1, stats + C4_OFF, fg1, fb1,
                                                               s4p, 128, 1024);
  pack_wfc<<<dim3(1, 1, 1), B, 0, stream>>>(fw1, w4p, 10, 1024);
  fc_bin_scale<<<dim3(5), B, 0, stream>>>(s4p, w4p, fp1, scl, (float*)d_out, 128, 10, 16);
}

// Round 4
// 625.729 us; speedup vs baseline: 1.6613x; 1.1386x over previous
//
#include <hip/hip_runtime.h>
#include <cstdint>
#include <cstddef>

#define BN_EPS 1e-5

// ---------------- reductions (fp64 for exact sign decisions) ----------------

__global__ void zero_d(double* p, int n) {
  int i = blockIdx.x * blockDim.x + threadIdx.x;
  if (i < n) p[i] = 0.0;
}

// one contiguous HW plane per block: grid (C, N), x[(n*C+c)*HW ...]
__global__ void reduce_plane(const float* __restrict__ x, double* __restrict__ sums,
                             int C, int HW) {
  int c = blockIdx.x, n = blockIdx.y;
  const float* p = x + ((long)n * C + c) * HW;
  double s = 0.0, s2 = 0.0;
  for (int i = threadIdx.x; i < HW; i += blockDim.x) {
    double v = (double)p[i];
    s += v; s2 += v * v;
  }
  for (int o = 32; o > 0; o >>= 1) {
    s  += __shfl_down(s, o, 64);
    s2 += __shfl_down(s2, o, 64);
  }
  __shared__ double ls[4], ls2[4];
  int lane = threadIdx.x & 63, w = threadIdx.x >> 6;
  if (lane == 0) { ls[w] = s; ls2[w] = s2; }
  __syncthreads();
  if (threadIdx.x == 0) {
    double a = 0, b = 0;
    for (int i = 0; i < 4; i++) { a += ls[i]; b += ls2[i]; }
    atomicAdd(&sums[2 * c], a);
    atomicAdd(&sums[2 * c + 1], b);
  }
}

// channel-last reduce: x [rows][C]; grid (C/64, RB), block 256 (4 waves).
// lane owns channel c; wave reads 256 B contiguous per row -> fully coalesced.
__global__ void reduce_cl(const float* __restrict__ x, double* __restrict__ sums,
                          int C, long rows) {
  int lane = threadIdx.x & 63, wv = threadIdx.x >> 6;
  int c = blockIdx.x * 64 + lane;
  double s = 0.0, s2 = 0.0;
  for (long r = blockIdx.y * 4 + wv; r < rows; r += (long)gridDim.y * 4) {
    double v = (double)x[r * C + c];
    s += v; s2 += v * v;
  }
  __shared__ double ls[4][64], ls2[4][64];
  ls[wv][lane] = s; ls2[wv][lane] = s2;
  __syncthreads();
  if (threadIdx.x < 64) {
    double a = ls[0][lane] + ls[1][lane] + ls[2][lane] + ls[3][lane];
    double b = ls2[0][lane] + ls2[1][lane] + ls2[2][lane] + ls2[3][lane];
    atomicAdd(&sums[2 * c], a);
    atomicAdd(&sums[2 * c + 1], b);
  }
}

// per-feature sum/sumsq over rows of an R x F matrix (lanes = consecutive f: coalesced)
__global__ void reduce_cols(const float* __restrict__ x, double* __restrict__ sums,
                            int R, int F) {
  int f = blockIdx.x * blockDim.x + threadIdx.x;
  if (f >= F) return;
  double s = 0.0, s2 = 0.0;
  for (int r = 0; r < R; r++) {
    double v = (double)x[(long)r * F + f];
    s += v; s2 += v * v;
  }
  sums[2 * f] = s;
  sums[2 * f + 1] = s2;
}

__global__ void finalize_stats(const double* __restrict__ sums, double2* __restrict__ st,
                               int C, double cnt) {
  int c = blockIdx.x * blockDim.x + threadIdx.x;
  if (c >= C) return;
  double m = sums[2 * c] / cnt;
  double v = sums[2 * c + 1] / cnt - m * m;
  st[c] = make_double2(m, 1.0 / sqrt(v + BN_EPS));
}

// ---------------- ballot-based sign/pack kernels ----------------

// conv1 input -> row bitmasks [n][3][64]; lane = x-pixel, one wave per row word
__global__ void pack_bits_c1(const float* __restrict__ x, const double2* __restrict__ st,
                             const float* __restrict__ g, const float* __restrict__ b,
                             uint64_t* __restrict__ rows) {
  int wid = blockIdx.x * 4 + (threadIdx.x >> 6);
  int lane = threadIdx.x & 63;
  int n = wid / 192, rem = wid % 192;
  int ci = rem >> 6, y = rem & 63;
  double2 s = st[ci];
  float xv = x[(((long)n * 3 + ci) * 64 + y) * 64 + lane];
  float xn = (float)(((double)xv - s.x) * s.y) * g[ci] + b[ci];
  uint64_t m = __ballot(xn > 0.f);
  if (lane == 0) rows[wid] = m;
}

// conv1 weights -> 27-bit masks, bit j = ci*9+ky*3+kx
__global__ void pack_wc1(const float* __restrict__ w, uint32_t* __restrict__ wm) {
  int co = threadIdx.x;
  uint32_t m = 0;
  for (int j = 0; j < 27; j++) m |= (uint32_t)(w[co * 27 + j] > 0.f) << j;
  wm[co] = m;
}

// channel-last activations [rows][C] -> packed [rows][W]; one wave per word (bit = lane = channel)
__global__ void pack_cl(const float* __restrict__ acl, const double2* __restrict__ st,
                        const float* __restrict__ g, const float* __restrict__ b,
                        uint64_t* __restrict__ out, int C, long nwords, int lw) {
  long wid = (long)blockIdx.x * 4 + (threadIdx.x >> 6);
  if (wid >= nwords) return;
  int lane = threadIdx.x & 63;
  long row = wid >> lw;
  int w = (int)(wid & ((1 << lw) - 1));
  int c = w * 64 + lane;
  double2 s = st[c];
  float xv = acl[row * C + c];
  float xn = (float)(((double)xv - s.x) * s.y) * g[c] + b[c];
  uint64_t m = __ballot(xn > 0.f);
  if (lane == 0) out[wid] = m;
}

// pack conv weights [co][ci][3][3] -> [co][tap][W]
__global__ void pack_wconv(const float* __restrict__ w, uint64_t* __restrict__ out,
                           int CO, int CI, int W) {
  int i = blockIdx.x * blockDim.x + threadIdx.x;
  int total = CO * 9 * W;
  if (i >= total) return;
  int wd = i % W;
  int t = i / W;
  int tap = t % 9, co = t / 9;
  uint64_t bits = 0;
  for (int k = 0; k < 64; k++) {
    int ci = wd * 64 + k;
    bits |= (uint64_t)(w[((long)co * CI + ci) * 9 + tap] > 0.f) << k;
  }
  out[i] = bits;
}

// BN1d rows [R][F] -> [r][Wf][2] (sign word, nonzero word); one wave per word pair
__global__ void pack_nz(const float* __restrict__ x, const double2* __restrict__ st,
                        const float* __restrict__ g, const float* __restrict__ b,
                        uint64_t* __restrict__ out, int R, int F) {
  int Wf = F >> 6;
  long wid = (long)blockIdx.x * 4 + (threadIdx.x >> 6);
  if (wid >= (long)R * Wf) return;
  int lane = threadIdx.x & 63;
  long r = wid / Wf;
  int w = (int)(wid % Wf);
  int f = w * 64 + lane;
  double2 s = st[f];
  double d = (double)x[r * F + f] - s.x;  // exact for lattice values
  float xn = (float)(d * s.y) * g[f] + b[f];
  uint64_t sm = __ballot(xn > 0.f);
  uint64_t nm = __ballot(d != 0.0);
  if (lane == 0) { out[2 * wid] = sm; out[2 * wid + 1] = nm; }
}

// fc weights [O][F] -> [o][F/64]; one wave per word, perfectly coalesced
__global__ void pack_wfc2(const float* __restrict__ w, uint64_t* __restrict__ out,
                          int O, int F) {
  int Wf = F >> 6;
  long wid = (long)blockIdx.x * 4 + (threadIdx.x >> 6);
  if (wid >= (long)O * Wf) return;
  int lane = threadIdx.x & 63;
  long o = wid / Wf;
  int wd = (int)(wid % Wf);
  uint64_t m = __ballot(w[o * F + wd * 64 + lane] > 0.f);
  if (lane == 0) out[wid] = m;
}

// ---------------- fused conv + maxpool + prelu ----------------

// conv1 via 27-bit xnor-popcount. rows [n][3][64], wm [128], out channel-last [n][961][128]
__global__ __launch_bounds__(256) void conv1_pool3(const uint64_t* __restrict__ rows,
                                                   const uint32_t* __restrict__ wm,
                                                   const float* __restrict__ cp,
                                                   float* __restrict__ out) {
  __shared__ uint64_t rL[192];
  __shared__ uint32_t wL[128];
  __shared__ uint32_t mL[61 * 4];
  int n = blockIdx.y, chunk = blockIdx.x, t = threadIdx.x;
  if (t < 192) rL[t] = rows[n * 192 + t];
  if (t < 128) wL[t] = wm[t];
  __syncthreads();
  if (t < 244) {  // build the 4 pool-quadrant masks per position, shared by all co
    int pl = t >> 2, quad = t & 3;
    int pos = chunk * 61 + pl;
    if (pos < 961) {
      int py = pos / 31, px = pos - py * 31;
      int cy = 2 * py + (quad >> 1), cx = 2 * px + (quad & 1);
      uint32_t m = 0;
#pragma unroll
      for (int ci = 0; ci < 3; ci++)
#pragma unroll
        for (int ky = 0; ky < 3; ky++)
          m |= (uint32_t)((rL[ci * 64 + cy + ky] >> cx) & 7) << (ci * 9 + ky * 3);
      mL[pl * 4 + quad] = m;
    }
  }
  __syncthreads();
  int co = t & 127, slot = t >> 7;
  float alpha = cp[0];
  uint32_t w = wL[co];
  for (int i = slot; i < 61; i += 2) {
    int pos = chunk * 61 + i;
    if (pos >= 961) break;
    int p0 = __popc(mL[4 * i] ^ w);
    int p1 = __popc(mL[4 * i + 1] ^ w);
    int p2 = __popc(mL[4 * i + 2] ^ w);
    int p3 = __popc(mL[4 * i + 3] ^ w);
    int dot = 27 - 2 * min(min(p0, p1), min(p2, p3));
    float f = (float)dot;
    out[((long)n * 961 + pos) * 128 + co] = dot >= 0 ? f : alpha * f;
  }
}

// xnor-popcount conv + pool + prelu, LDS-staged. in [n][IH][IH][W], wt [co][9][W].
// CL=true: out [n][PH*PH][CO] (channel-last); else [n][CO][PH*PH].
template <int W, int IH, int PH, int POSCH, bool CL>
__global__ __launch_bounds__(256) void convp_pool2(
    const uint64_t* __restrict__ in, const uint64_t* __restrict__ wt,
    const float* __restrict__ cp, float* __restrict__ out, int CO) {
  constexpr int PS = 9 * W + 1;
  __shared__ uint64_t sIn[IH * IH * W];
  __shared__ uint64_t sW[64 * PS];
  int n = blockIdx.y;
  int cg = blockIdx.x / POSCH;
  int chunk = blockIdx.x % POSCH;
  int t = threadIdx.x;
  const uint64_t* src = in + (long)n * (IH * IH * W);
  for (int i = t; i < IH * IH * W; i += 256) sIn[i] = src[i];
  int cobase = cg * 64;
  for (int i = t; i < 64 * 9 * W; i += 256) {
    int col = i / (9 * W), r = i - col * (9 * W);
    sW[col * PS + r] = wt[((long)(cobase + col)) * (9 * W) + r];
  }
  __syncthreads();
  int co_l = t & 63;
  int slot = t >> 6;
  float alpha = cp[0];
  int co = cobase + co_l;
  const uint64_t* wrow = &sW[co_l * PS];
  for (int pos = chunk * 4 + slot; pos < PH * PH; pos += POSCH * 4) {
    int py = pos / PH, px = pos % PH;
    int pc00 = 0, pc01 = 0, pc10 = 0, pc11 = 0;
#pragma unroll
    for (int ky = 0; ky < 3; ky++) {
#pragma unroll
      for (int kx = 0; kx < 3; kx++) {
        uint64_t wv[W];
#pragma unroll
        for (int wd = 0; wd < W; wd++) wv[wd] = wrow[(ky * 3 + kx) * W + wd];
        const uint64_t* pr0 = &sIn[((2 * py + ky) * IH + (2 * px + kx)) * W];
        const uint64_t* pr1 = &sIn[((2 * py + 1 + ky) * IH + (2 * px + kx)) * W];
        int a0 = 0, a1 = 0, a2 = 0, a3 = 0;
#pragma unroll
        for (int wd = 0; wd < W; wd++) {
          a0 += __popcll(pr0[wd] ^ wv[wd]);
          a1 += __popcll(pr0[W + wd] ^ wv[wd]);
          a2 += __popcll(pr1[wd] ^ wv[wd]);
          a3 += __popcll(pr1[W + wd] ^ wv[wd]);
        }
        pc00 += a0; pc01 += a1; pc10 += a2; pc11 += a3;
      }
    }
    int pmin = min(min(pc00, pc01), min(pc10, pc11));
    int dot = 9 * 64 * W - 2 * pmin;
    float f = (float)dot;
    long idx = CL ? (((long)n * PH * PH + pos) * CO + co)
                  : (((long)n * CO + co) * PH * PH + pos);
    out[idx] = dot >= 0 ? f : alpha * f;
  }
}

// ---------------- binary fc (with nonzero mask on activations) ----------------

__global__ void fc_bin(const uint64_t* __restrict__ xp, const uint64_t* __restrict__ wp,
                       const float* __restrict__ cp, float* __restrict__ out,
                       int O, int Wf) {
  __shared__ uint64_t xs[288], xz[288];
  int r = blockIdx.y;
  for (int i = threadIdx.x; i < Wf; i += blockDim.x) {
    xs[i] = xp[((long)r * Wf + i) * 2];
    xz[i] = xp[((long)r * Wf + i) * 2 + 1];
  }
  __syncthreads();
  int o = blockIdx.x * blockDim.x + threadIdx.x;
  if (o >= O) return;
  int pc = 0, nzc = 0;
  const uint64_t* wr = wp + (long)o * Wf;
  for (int wd = 0; wd < Wf; wd++) {
    uint64_t nz = xz[wd];
    pc  += __popcll((xs[wd] ^ wr[wd]) & nz);
    nzc += __popcll(nz);
  }
  int dot = nzc - 2 * pc;
  float f = (float)dot;
  float alpha = cp[0];
  out[(long)r * O + o] = dot >= 0 ? f : alpha * f;
}

__global__ void fc_bin_scale(const uint64_t* __restrict__ xp, const uint64_t* __restrict__ wp,
                             const float* __restrict__ cp, const float* __restrict__ scale,
                             float* __restrict__ out, int R, int O, int Wf) {
  int i = blockIdx.x * blockDim.x + threadIdx.x;
  if (i >= R * O) return;
  int o = i % O, r = i / O;
  int pc = 0, nzc = 0;
  for (int wd = 0; wd < Wf; wd++) {
    uint64_t nz = xp[((long)r * Wf + wd) * 2 + 1];
    pc  += __popcll((xp[((long)r * Wf + wd) * 2] ^ wp[(long)o * Wf + wd]) & nz);
    nzc += __popcll(nz);
  }
  int dot = nzc - 2 * pc;
  float f = (float)dot;
  float alpha = cp[0];
  f = dot >= 0 ? f : alpha * f;
  out[i] = f * scale[0];
}

// ---------------- launch ----------------

extern "C" void kernel_launch(void* const* d_in, const int* in_sizes, int n_in,
                              void* d_out, int out_size, void* d_ws, size_t ws_size,
                              hipStream_t stream) {
  const float* x   = (const float*)d_in[0];
  const float* cg0 = (const float*)d_in[1];
  const float* cb0 = (const float*)d_in[2];
  const float* cw0 = (const float*)d_in[3];
  const float* cp0 = (const float*)d_in[4];
  const float* cg1 = (const float*)d_in[5];
  const float* cb1 = (const float*)d_in[6];
  const float* cw1 = (const float*)d_in[7];
  const float* cp1 = (const float*)d_in[8];
  const float* cg2 = (const float*)d_in[9];
  const float* cb2 = (const float*)d_in[10];
  const float* cw2 = (const float*)d_in[11];
  const float* cp2 = (const float*)d_in[12];
  const float* fg0 = (const float*)d_in[13];
  const float* fb0 = (const float*)d_in[14];
  const float* fw0 = (const float*)d_in[15];
  const float* fp0 = (const float*)d_in[16];
  const float* fg1 = (const float*)d_in[17];
  const float* fb1 = (const float*)d_in[18];
  const float* fw1 = (const float*)d_in[19];
  const float* fp1 = (const float*)d_in[20];
  const float* scl = (const float*)d_in[21];

  char* ws = (char*)d_ws;
  size_t off = 0;
  auto alloc = [&](size_t bytes) {
    size_t r = off;
    off += (bytes + 255) & ~(size_t)255;
    return r;
  };
  const int C0_OFF = 0, C1_OFF = 16, C2_OFF = 160, C3_OFF = 448, C4_OFF = 18944;
  const int NCH = 19968;

  double*   sums  = (double*)(ws + alloc((size_t)NCH * 2 * sizeof(double)));
  double2*  stats = (double2*)(ws + alloc((size_t)NCH * sizeof(double2)));
  uint64_t* rows0 = (uint64_t*)(ws + alloc(128L * 3 * 64 * 8));
  uint32_t* wm1   = (uint32_t*)(ws + alloc(128L * 4));
  float*    a1    = (float*)(ws + alloc(128L * 961 * 128 * 4));   // channel-last
  uint64_t* s1p   = (uint64_t*)(ws + alloc(128L * 961 * 2 * 8));
  uint64_t* w1p   = (uint64_t*)(ws + alloc(256L * 9 * 2 * 8));
  float*    a2    = (float*)(ws + alloc(128L * 196 * 256 * 4));   // channel-last
  uint64_t* s2p   = (uint64_t*)(ws + alloc(128L * 196 * 4 * 8));
  uint64_t* w2p   = (uint64_t*)(ws + alloc(512L * 9 * 4 * 8));
  float*    a3    = (float*)(ws + alloc(128L * 512 * 36 * 4));    // channel-major (reshape order)
  uint64_t* s3p   = (uint64_t*)(ws + alloc(128L * 288 * 2 * 8));
  uint64_t* w3p   = (uint64_t*)(ws + alloc(1024L * 288 * 8));
  float*    f1    = (float*)(ws + alloc(128L * 1024 * 4));
  uint64_t* s4p   = (uint64_t*)(ws + alloc(128L * 16 * 2 * 8));
  uint64_t* w4p   = (uint64_t*)(ws + alloc(10L * 16 * 8));

  const int B = 256;

  zero_d<<<dim3(4), B, 0, stream>>>(sums, 832);  // atomic regions C0..C2 only

  // ---- block 0: BN(x) -> sign-bits -> conv1(popcount) -> pool -> prelu ----
  reduce_plane<<<dim3(3, 128), B, 0, stream>>>(x, sums + 2 * C0_OFF, 3, 4096);
  finalize_stats<<<1, 64, 0, stream>>>(sums + 2 * C0_OFF, stats + C0_OFF, 3, 524288.0);
  pack_bits_c1<<<dim3(6144), B, 0, stream>>>(x, stats + C0_OFF, cg0, cb0, rows0);
  pack_wc1<<<1, 128, 0, stream>>>(cw0, wm1);
  conv1_pool3<<<dim3(16, 128), B, 0, stream>>>(rows0, wm1, cp0, a1);

  // ---- block 1: BN(a1) -> pack -> conv2 -> pool -> prelu ----
  reduce_cl<<<dim3(2, 128), B, 0, stream>>>(a1, sums + 2 * C1_OFF, 128, 123008L);
  finalize_stats<<<1, 128, 0, stream>>>(sums + 2 * C1_OFF, stats + C1_OFF, 128, 123008.0);
  pack_cl<<<dim3(61504), B, 0, stream>>>(a1, stats + C1_OFF, cg1, cb1, s1p, 128, 246016L, 1);
  pack_wconv<<<dim3(18), B, 0, stream>>>(cw1, w1p, 256, 128, 2);
  convp_pool2<2, 31, 14, 4, true><<<dim3(16, 128), B, 0, stream>>>(s1p, w1p, cp1, a2, 256);

  // ---- block 2: BN(a2) -> pack -> conv3 -> pool -> prelu ----
  reduce_cl<<<dim3(4, 64), B, 0, stream>>>(a2, sums + 2 * C2_OFF, 256, 25088L);
  finalize_stats<<<1, 256, 0, stream>>>(sums + 2 * C2_OFF, stats + C2_OFF, 256, 25088.0);
  pack_cl<<<dim3(25088), B, 0, stream>>>(a2, stats + C2_OFF, cg2, cb2, s2p, 256, 100352L, 2);
  pack_wconv<<<dim3(72), B, 0, stream>>>(cw2, w2p, 512, 256, 4);
  convp_pool2<4, 14, 6, 2, false><<<dim3(16, 128), B, 0, stream>>>(s2p, w2p, cp2, a3, 512);

  // ---- fc 0: BN1d -> sign @ sign(W).T -> prelu ----
  reduce_cols<<<dim3(72), B, 0, stream>>>(a3, sums + 2 * C3_OFF, 128, 18432);
  finalize_stats<<<dim3(72), B, 0, stream>>>(sums + 2 * C3_OFF, stats + C3_OFF, 18432, 128.0);
  pack_nz<<<dim3(9216), B, 0, stream>>>(a3, stats + C3_OFF, fg0, fb0, s3p, 128, 18432);
  pack_wfc2<<<dim3(73728), B, 0, stream>>>(fw0, w3p, 1024, 18432);
  fc_bin<<<dim3(4, 128), B, 0, stream>>>(s3p, w3p, fp0, f1, 1024, 288);

  // ---- fc 1: BN1d -> sign @ sign(W).T -> prelu -> scale ----
  reduce_cols<<<dim3(4), B, 0, stream>>>(f1, sums + 2 * C4_OFF, 128, 1024);
  finalize_stats<<<dim3(4), B, 0, stream>>>(sums + 2 * C4_OFF, stats + C4_OFF, 1024, 128.0);
  pack_nz<<<dim3(512), B, 0, stream>>>(f1, stats + C4_OFF, fg1, fb1, s4p, 128, 1024);
  pack_wfc2<<<dim3(40), B, 0, stream>>>(fw1, w4p, 10, 1024);
  fc_bin_scale<<<dim3(5), B, 0, stream>>>(s4p, w4p, fp1, scl, (float*)d_out, 128, 10, 16);
}

// Round 5
// 611.085 us; speedup vs baseline: 1.7011x; 1.0240x over previous
//
#include <hip/hip_runtime.h>
#include <cstdint>
#include <cstddef>

#define BN_EPS 1e-5

// ---------------- reductions (fp64 for exact sign decisions) ----------------

__global__ void zero_d(double* p, int n) {
  int i = blockIdx.x * blockDim.x + threadIdx.x;
  if (i < n) p[i] = 0.0;
}

// one contiguous HW plane per block: grid (C, N), x[(n*C+c)*HW ...]
__global__ void reduce_plane(const float* __restrict__ x, double* __restrict__ sums,
                             int C, int HW) {
  int c = blockIdx.x, n = blockIdx.y;
  const float* p = x + ((long)n * C + c) * HW;
  double s = 0.0, s2 = 0.0;
  for (int i = threadIdx.x; i < HW; i += blockDim.x) {
    double v = (double)p[i];
    s += v; s2 += v * v;
  }
  for (int o = 32; o > 0; o >>= 1) {
    s  += __shfl_down(s, o, 64);
    s2 += __shfl_down(s2, o, 64);
  }
  __shared__ double ls[4], ls2[4];
  int lane = threadIdx.x & 63, w = threadIdx.x >> 6;
  if (lane == 0) { ls[w] = s; ls2[w] = s2; }
  __syncthreads();
  if (threadIdx.x == 0) {
    double a = 0, b = 0;
    for (int i = 0; i < 4; i++) { a += ls[i]; b += ls2[i]; }
    atomicAdd(&sums[2 * c], a);
    atomicAdd(&sums[2 * c + 1], b);
  }
}

// channel-last reduce: x [rows][C]; grid (C/64, RB), block 256 (4 waves).
__global__ void reduce_cl(const float* __restrict__ x, double* __restrict__ sums,
                          int C, long rows) {
  int lane = threadIdx.x & 63, wv = threadIdx.x >> 6;
  int c = blockIdx.x * 64 + lane;
  double s = 0.0, s2 = 0.0;
  for (long r = blockIdx.y * 4 + wv; r < rows; r += (long)gridDim.y * 4) {
    double v = (double)x[r * C + c];
    s += v; s2 += v * v;
  }
  __shared__ double ls[4][64], ls2[4][64];
  ls[wv][lane] = s; ls2[wv][lane] = s2;
  __syncthreads();
  if (threadIdx.x < 64) {
    double a = ls[0][lane] + ls[1][lane] + ls[2][lane] + ls[3][lane];
    double b = ls2[0][lane] + ls2[1][lane] + ls2[2][lane] + ls2[3][lane];
    atomicAdd(&sums[2 * c], a);
    atomicAdd(&sums[2 * c + 1], b);
  }
}

// per-feature sum/sumsq over rows of an R x F matrix (lanes = consecutive f)
__global__ void reduce_cols(const float* __restrict__ x, double* __restrict__ sums,
                            int R, int F) {
  int f = blockIdx.x * blockDim.x + threadIdx.x;
  if (f >= F) return;
  double s = 0.0, s2 = 0.0;
  for (int r = 0; r < R; r++) {
    double v = (double)x[(long)r * F + f];
    s += v; s2 += v * v;
  }
  sums[2 * f] = s;
  sums[2 * f + 1] = s2;
}

__global__ void finalize_stats(const double* __restrict__ sums, double2* __restrict__ st,
                               int C, double cnt) {
  int c = blockIdx.x * blockDim.x + threadIdx.x;
  if (c >= C) return;
  double m = sums[2 * c] / cnt;
  double v = sums[2 * c + 1] / cnt - m * m;
  st[c] = make_double2(m, 1.0 / sqrt(v + BN_EPS));
}

// ---------------- ballot-based sign/pack kernels ----------------

// conv1 input -> row bitmasks [n][3][64]; lane = x-pixel, one wave per row word
__global__ void pack_bits_c1(const float* __restrict__ x, const double2* __restrict__ st,
                             const float* __restrict__ g, const float* __restrict__ b,
                             uint64_t* __restrict__ rows) {
  int wid = blockIdx.x * 4 + (threadIdx.x >> 6);
  int lane = threadIdx.x & 63;
  int n = wid / 192, rem = wid % 192;
  int ci = rem >> 6, y = rem & 63;
  double2 s = st[ci];
  float xv = x[(((long)n * 3 + ci) * 64 + y) * 64 + lane];
  float xn = (float)(((double)xv - s.x) * s.y) * g[ci] + b[ci];
  uint64_t m = __ballot(xn > 0.f);
  if (lane == 0) rows[wid] = m;
}

// conv1 weights -> 27-bit masks, bit j = ci*9+ky*3+kx
__global__ void pack_wc1(const float* __restrict__ w, uint32_t* __restrict__ wm) {
  int co = threadIdx.x;
  uint32_t m = 0;
  for (int j = 0; j < 27; j++) m |= (uint32_t)(w[co * 27 + j] > 0.f) << j;
  wm[co] = m;
}

// channel-last activations [rows][C] -> packed [rows][W]; one wave per word
__global__ void pack_cl(const float* __restrict__ acl, const double2* __restrict__ st,
                        const float* __restrict__ g, const float* __restrict__ b,
                        uint64_t* __restrict__ out, int C, long nwords, int lw) {
  long wid = (long)blockIdx.x * 4 + (threadIdx.x >> 6);
  if (wid >= nwords) return;
  int lane = threadIdx.x & 63;
  long row = wid >> lw;
  int w = (int)(wid & ((1 << lw) - 1));
  int c = w * 64 + lane;
  double2 s = st[c];
  float xv = acl[row * C + c];
  float xn = (float)(((double)xv - s.x) * s.y) * g[c] + b[c];
  uint64_t m = __ballot(xn > 0.f);
  if (lane == 0) out[wid] = m;
}

// pack conv weights [co][ci][3][3] -> [co][tap][W]
__global__ void pack_wconv(const float* __restrict__ w, uint64_t* __restrict__ out,
                           int CO, int CI, int W) {
  int i = blockIdx.x * blockDim.x + threadIdx.x;
  int total = CO * 9 * W;
  if (i >= total) return;
  int wd = i % W;
  int t = i / W;
  int tap = t % 9, co = t / 9;
  uint64_t bits = 0;
  for (int k = 0; k < 64; k++) {
    int ci = wd * 64 + k;
    bits |= (uint64_t)(w[((long)co * CI + ci) * 9 + tap] > 0.f) << k;
  }
  out[i] = bits;
}

// BN1d rows [R][F] -> [r][Wf][2] (sign word, nonzero word); one wave per word pair
__global__ void pack_nz(const float* __restrict__ x, const double2* __restrict__ st,
                        const float* __restrict__ g, const float* __restrict__ b,
                        uint64_t* __restrict__ out, int R, int F) {
  int Wf = F >> 6;
  long wid = (long)blockIdx.x * 4 + (threadIdx.x >> 6);
  if (wid >= (long)R * Wf) return;
  int lane = threadIdx.x & 63;
  long r = wid / Wf;
  int w = (int)(wid % Wf);
  int f = w * 64 + lane;
  double2 s = st[f];
  double d = (double)x[r * F + f] - s.x;  // exact for lattice values
  float xn = (float)(d * s.y) * g[f] + b[f];
  uint64_t sm = __ballot(xn > 0.f);
  uint64_t nm = __ballot(d != 0.0);
  if (lane == 0) { out[2 * wid] = sm; out[2 * wid + 1] = nm; }
}

// fc weights [O][F] -> [o][F/64]; one wave per word, perfectly coalesced
__global__ void pack_wfc2(const float* __restrict__ w, uint64_t* __restrict__ out,
                          int O, int F) {
  int Wf = F >> 6;
  long wid = (long)blockIdx.x * 4 + (threadIdx.x >> 6);
  if (wid >= (long)O * Wf) return;
  int lane = threadIdx.x & 63;
  long o = wid / Wf;
  int wd = (int)(wid % Wf);
  uint64_t m = __ballot(w[o * F + wd * 64 + lane] > 0.f);
  if (lane == 0) out[wid] = m;
}

// ---------------- fused conv + maxpool + prelu ----------------

// conv1 via 27-bit xnor-popcount. rows [n][3][64], wm [128], out channel-last [n][961][128]
__global__ __launch_bounds__(256) void conv1_pool3(const uint64_t* __restrict__ rows,
                                                   const uint32_t* __restrict__ wm,
                                                   const float* __restrict__ cp,
                                                   float* __restrict__ out) {
  __shared__ uint64_t rL[192];
  __shared__ uint32_t wL[128];
  __shared__ uint32_t mL[61 * 4];
  int n = blockIdx.y, chunk = blockIdx.x, t = threadIdx.x;
  if (t < 192) rL[t] = rows[n * 192 + t];
  if (t < 128) wL[t] = wm[t];
  __syncthreads();
  if (t < 244) {
    int pl = t >> 2, quad = t & 3;
    int pos = chunk * 61 + pl;
    if (pos < 961) {
      int py = pos / 31, px = pos - py * 31;
      int cy = 2 * py + (quad >> 1), cx = 2 * px + (quad & 1);
      uint32_t m = 0;
#pragma unroll
      for (int ci = 0; ci < 3; ci++)
#pragma unroll
        for (int ky = 0; ky < 3; ky++)
          m |= (uint32_t)((rL[ci * 64 + cy + ky] >> cx) & 7) << (ci * 9 + ky * 3);
      mL[pl * 4 + quad] = m;
    }
  }
  __syncthreads();
  int co = t & 127, slot = t >> 7;
  float alpha = cp[0];
  uint32_t w = wL[co];
  for (int i = slot; i < 61; i += 2) {
    int pos = chunk * 61 + i;
    if (pos >= 961) break;
    int p0 = __popc(mL[4 * i] ^ w);
    int p1 = __popc(mL[4 * i + 1] ^ w);
    int p2 = __popc(mL[4 * i + 2] ^ w);
    int p3 = __popc(mL[4 * i + 3] ^ w);
    int dot = 27 - 2 * min(min(p0, p1), min(p2, p3));
    float f = (float)dot;
    out[((long)n * 961 + pos) * 128 + co] = dot >= 0 ? f : alpha * f;
  }
}

// xnor-popcount conv + pool + prelu, v3: weights in REGISTERS (loop-invariant per
// thread; v2 re-read them from LDS every position with 4-way bank aliasing), patch
// processed one input-row at a time in registers; LDS holds only the image.
// in [n][IH][IH][W], wt [co][9][W].  CL: out [n][PH*PH][CO] else [n][CO][PH*PH].
template <int W, int IH, int PH, int POSCH, bool CL>
__global__ __launch_bounds__(256) void convp_pool3(
    const uint64_t* __restrict__ in, const uint64_t* __restrict__ wt,
    const float* __restrict__ cp, float* __restrict__ out, int CO) {
  __shared__ uint64_t sIn[IH * IH * W];
  int n = blockIdx.y;
  int cg = blockIdx.x / POSCH;
  int chunk = blockIdx.x % POSCH;
  int t = threadIdx.x;
  const uint64_t* src = in + (long)n * (IH * IH * W);
  for (int i = t; i < IH * IH * W; i += 256) sIn[i] = src[i];
  int lane = t & 63;
  int slot = t >> 6;
  int co = cg * 64 + lane;
  uint64_t wr[9 * W];
  const uint64_t* wg = wt + (long)co * (9 * W);
#pragma unroll
  for (int i = 0; i < 9 * W; i++) wr[i] = wg[i];
  __syncthreads();
  float alpha = cp[0];
  for (int pos = chunk * 4 + slot; pos < PH * PH; pos += POSCH * 4) {
    int py = pos / PH, px = pos % PH;
    int a00 = 0, a01 = 0, a10 = 0, a11 = 0;
#pragma unroll
    for (int cy = 0; cy < 4; cy++) {
      uint64_t row[4 * W];
      const uint64_t* rp = &sIn[((2 * py + cy) * IH + 2 * px) * W];
#pragma unroll
      for (int i = 0; i < 4 * W; i++) row[i] = rp[i];
#pragma unroll
      for (int dy = 0; dy < 2; dy++) {
        int ky = cy - dy;
        if (ky < 0 || ky > 2) continue;  // compile-time folded
#pragma unroll
        for (int dx = 0; dx < 2; dx++) {
          int a = 0;
#pragma unroll
          for (int kx = 0; kx < 3; kx++)
#pragma unroll
            for (int wd = 0; wd < W; wd++)
              a += __popcll(row[(dx + kx) * W + wd] ^ wr[(ky * 3 + kx) * W + wd]);
          if (dy == 0) { if (dx == 0) a00 += a; else a01 += a; }
          else         { if (dx == 0) a10 += a; else a11 += a; }
        }
      }
    }
    int pmin = min(min(a00, a01), min(a10, a11));
    int dot = 9 * 64 * W - 2 * pmin;
    float f = (float)dot;
    long idx = CL ? (((long)n * PH * PH + pos) * CO + co)
                  : (((long)n * CO + co) * PH * PH + pos);
    out[idx] = dot >= 0 ? f : alpha * f;
  }
}

// ---------------- binary fc (with nonzero mask on activations) ----------------

__global__ void fc_bin(const uint64_t* __restrict__ xp, const uint64_t* __restrict__ wp,
                       const float* __restrict__ cp, float* __restrict__ out,
                       int O, int Wf) {
  __shared__ uint64_t xs[288], xz[288];
  int r = blockIdx.y;
  for (int i = threadIdx.x; i < Wf; i += blockDim.x) {
    xs[i] = xp[((long)r * Wf + i) * 2];
    xz[i] = xp[((long)r * Wf + i) * 2 + 1];
  }
  __syncthreads();
  int o = blockIdx.x * blockDim.x + threadIdx.x;
  if (o >= O) return;
  int pc = 0, nzc = 0;
  const uint64_t* wr = wp + (long)o * Wf;
  for (int wd = 0; wd < Wf; wd++) {
    uint64_t nz = xz[wd];
    pc  += __popcll((xs[wd] ^ wr[wd]) & nz);
    nzc += __popcll(nz);
  }
  int dot = nzc - 2 * pc;
  float f = (float)dot;
  float alpha = cp[0];
  out[(long)r * O + o] = dot >= 0 ? f : alpha * f;
}

__global__ void fc_bin_scale(const uint64_t* __restrict__ xp, const uint64_t* __restrict__ wp,
                             const float* __restrict__ cp, const float* __restrict__ scale,
                             float* __restrict__ out, int R, int O, int Wf) {
  int i = blockIdx.x * blockDim.x + threadIdx.x;
  if (i >= R * O) return;
  int o = i % O, r = i / O;
  int pc = 0, nzc = 0;
  for (int wd = 0; wd < Wf; wd++) {
    uint64_t nz = xp[((long)r * Wf + wd) * 2 + 1];
    pc  += __popcll((xp[((long)r * Wf + wd) * 2] ^ wp[(long)o * Wf + wd]) & nz);
    nzc += __popcll(nz);
  }
  int dot = nzc - 2 * pc;
  float f = (float)dot;
  float alpha = cp[0];
  f = dot >= 0 ? f : alpha * f;
  out[i] = f * scale[0];
}

// ---------------- launch ----------------

extern "C" void kernel_launch(void* const* d_in, const int* in_sizes, int n_in,
                              void* d_out, int out_size, void* d_ws, size_t ws_size,
                              hipStream_t stream) {
  const float* x   = (const float*)d_in[0];
  const float* cg0 = (const float*)d_in[1];
  const float* cb0 = (const float*)d_in[2];
  const float* cw0 = (const float*)d_in[3];
  const float* cp0 = (const float*)d_in[4];
  const float* cg1 = (const float*)d_in[5];
  const float* cb1 = (const float*)d_in[6];
  const float* cw1 = (const float*)d_in[7];
  const float* cp1 = (const float*)d_in[8];
  const float* cg2 = (const float*)d_in[9];
  const float* cb2 = (const float*)d_in[10];
  const float* cw2 = (const float*)d_in[11];
  const float* cp2 = (const float*)d_in[12];
  const float* fg0 = (const float*)d_in[13];
  const float* fb0 = (const float*)d_in[14];
  const float* fw0 = (const float*)d_in[15];
  const float* fp0 = (const float*)d_in[16];
  const float* fg1 = (const float*)d_in[17];
  const float* fb1 = (const float*)d_in[18];
  const float* fw1 = (const float*)d_in[19];
  const float* fp1 = (const float*)d_in[20];
  const float* scl = (const float*)d_in[21];

  char* ws = (char*)d_ws;
  size_t off = 0;
  auto alloc = [&](size_t bytes) {
    size_t r = off;
    off += (bytes + 255) & ~(size_t)255;
    return r;
  };
  const int C0_OFF = 0, C1_OFF = 16, C2_OFF = 160, C3_OFF = 448, C4_OFF = 18944;
  const int NCH = 19968;

  double*   sums  = (double*)(ws + alloc((size_t)NCH * 2 * sizeof(double)));
  double2*  stats = (double2*)(ws + alloc((size_t)NCH * sizeof(double2)));
  uint64_t* rows0 = (uint64_t*)(ws + alloc(128L * 3 * 64 * 8));
  uint32_t* wm1   = (uint32_t*)(ws + alloc(128L * 4));
  float*    a1    = (float*)(ws + alloc(128L * 961 * 128 * 4));   // channel-last
  uint64_t* s1p   = (uint64_t*)(ws + alloc(128L * 961 * 2 * 8));
  uint64_t* w1p   = (uint64_t*)(ws + alloc(256L * 9 * 2 * 8));
  float*    a2    = (float*)(ws + alloc(128L * 196 * 256 * 4));   // channel-last
  uint64_t* s2p   = (uint64_t*)(ws + alloc(128L * 196 * 4 * 8));
  uint64_t* w2p   = (uint64_t*)(ws + alloc(512L * 9 * 4 * 8));
  float*    a3    = (float*)(ws + alloc(128L * 512 * 36 * 4));    // channel-major (reshape order)
  uint64_t* s3p   = (uint64_t*)(ws + alloc(128L * 288 * 2 * 8));
  uint64_t* w3p   = (uint64_t*)(ws + alloc(1024L * 288 * 8));
  float*    f1    = (float*)(ws + alloc(128L * 1024 * 4));
  uint64_t* s4p   = (uint64_t*)(ws + alloc(128L * 16 * 2 * 8));
  uint64_t* w4p   = (uint64_t*)(ws + alloc(10L * 16 * 8));

  const int B = 256;

  zero_d<<<dim3(4), B, 0, stream>>>(sums, 832);  // atomic regions C0..C2 only

  // ---- block 0: BN(x) -> sign-bits -> conv1(popcount) -> pool -> prelu ----
  reduce_plane<<<dim3(3, 128), B, 0, stream>>>(x, sums + 2 * C0_OFF, 3, 4096);
  finalize_stats<<<1, 64, 0, stream>>>(sums + 2 * C0_OFF, stats + C0_OFF, 3, 524288.0);
  pack_bits_c1<<<dim3(6144), B, 0, stream>>>(x, stats + C0_OFF, cg0, cb0, rows0);
  pack_wc1<<<1, 128, 0, stream>>>(cw0, wm1);
  conv1_pool3<<<dim3(16, 128), B, 0, stream>>>(rows0, wm1, cp0, a1);

  // ---- block 1: BN(a1) -> pack -> conv2 -> pool -> prelu ----
  reduce_cl<<<dim3(2, 128), B, 0, stream>>>(a1, sums + 2 * C1_OFF, 128, 123008L);
  finalize_stats<<<1, 128, 0, stream>>>(sums + 2 * C1_OFF, stats + C1_OFF, 128, 123008.0);
  pack_cl<<<dim3(61504), B, 0, stream>>>(a1, stats + C1_OFF, cg1, cb1, s1p, 128, 246016L, 1);
  pack_wconv<<<dim3(18), B, 0, stream>>>(cw1, w1p, 256, 128, 2);
  convp_pool3<2, 31, 14, 4, true><<<dim3(16, 128), B, 0, stream>>>(s1p, w1p, cp1, a2, 256);

  // ---- block 2: BN(a2) -> pack -> conv3 -> pool -> prelu ----
  reduce_cl<<<dim3(4, 64), B, 0, stream>>>(a2, sums + 2 * C2_OFF, 256, 25088L);
  finalize_stats<<<1, 256, 0, stream>>>(sums + 2 * C2_OFF, stats + C2_OFF, 256, 25088.0);
  pack_cl<<<dim3(25088), B, 0, stream>>>(a2, stats + C2_OFF, cg2, cb2, s2p, 256, 100352L, 2);
  pack_wconv<<<dim3(72), B, 0, stream>>>(cw2, w2p, 512, 256, 4);
  convp_pool3<4, 14, 6, 2, false><<<dim3(16, 128), B, 0, stream>>>(s2p, w2p, cp2, a3, 512);

  // ---- fc 0: BN1d -> sign @ sign(W).T -> prelu ----
  reduce_cols<<<dim3(72), B, 0, stream>>>(a3, sums + 2 * C3_OFF, 128, 18432);
  finalize_stats<<<dim3(72), B, 0, stream>>>(sums + 2 * C3_OFF, stats + C3_OFF, 18432, 128.0);
  pack_nz<<<dim3(9216), B, 0, stream>>>(a3, stats + C3_OFF, fg0, fb0, s3p, 128, 18432);
  pack_wfc2<<<dim3(73728), B, 0, stream>>>(fw0, w3p, 1024, 18432);
  fc_bin<<<dim3(4, 128), B, 0, stream>>>(s3p, w3p, fp0, f1, 1024, 288);

  // ---- fc 1: BN1d -> sign @ sign(W).T -> prelu -> scale ----
  reduce_cols<<<dim3(4), B, 0, stream>>>(f1, sums + 2 * C4_OFF, 128, 1024);
  finalize_stats<<<dim3(4), B, 0, stream>>>(sums + 2 * C4_OFF, stats + C4_OFF, 1024, 128.0);
  pack_nz<<<dim3(512), B, 0, stream>>>(f1, stats + C4_OFF, fg1, fb1, s4p, 128, 1024);
  pack_wfc2<<<dim3(40), B, 0, stream>>>(fw1, w4p, 10, 1024);
  fc_bin_scale<<<dim3(5), B, 0, stream>>>(s4p, w4p, fp1, scl, (float*)d_out, 128, 10, 16);
}

// Round 6
// 531.241 us; speedup vs baseline: 1.9568x; 1.1503x over previous
//
#include <hip/hip_runtime.h>
#include <cstdint>
#include <cstddef>

#define BN_EPS 1e-5

// ---------------- reductions (fp64 for exact sign decisions) ----------------

__global__ void zero_d(double* p, int n) {
  int i = blockIdx.x * blockDim.x + threadIdx.x;
  if (i < n) p[i] = 0.0;
}

// one contiguous HW plane per block: grid (C, N)
__global__ void reduce_plane(const float* __restrict__ x, double* __restrict__ sums,
                             int C, int HW) {
  int c = blockIdx.x, n = blockIdx.y;
  const float* p = x + ((long)n * C + c) * HW;
  double s = 0.0, s2 = 0.0;
  for (int i = threadIdx.x; i < HW; i += blockDim.x) {
    double v = (double)p[i];
    s += v; s2 += v * v;
  }
  for (int o = 32; o > 0; o >>= 1) {
    s  += __shfl_down(s, o, 64);
    s2 += __shfl_down(s2, o, 64);
  }
  __shared__ double ls[4], ls2[4];
  int lane = threadIdx.x & 63, w = threadIdx.x >> 6;
  if (lane == 0) { ls[w] = s; ls2[w] = s2; }
  __syncthreads();
  if (threadIdx.x == 0) {
    double a = 0, b = 0;
    for (int i = 0; i < 4; i++) { a += ls[i]; b += ls2[i]; }
    atomicAdd(&sums[2 * c], a);
    atomicAdd(&sums[2 * c + 1], b);
  }
}

// channel-last reduce: x [rows][C]; grid (C/64, RB), block 256 (4 waves).
__global__ void reduce_cl(const float* __restrict__ x, double* __restrict__ sums,
                          int C, long rows) {
  int lane = threadIdx.x & 63, wv = threadIdx.x >> 6;
  int c = blockIdx.x * 64 + lane;
  double s = 0.0, s2 = 0.0;
  for (long r = blockIdx.y * 4 + wv; r < rows; r += (long)gridDim.y * 4) {
    double v = (double)x[r * C + c];
    s += v; s2 += v * v;
  }
  __shared__ double ls[4][64], ls2[4][64];
  ls[wv][lane] = s; ls2[wv][lane] = s2;
  __syncthreads();
  if (threadIdx.x < 64) {
    double a = ls[0][lane] + ls[1][lane] + ls[2][lane] + ls[3][lane];
    double b = ls2[0][lane] + ls2[1][lane] + ls2[2][lane] + ls2[3][lane];
    atomicAdd(&sums[2 * c], a);
    atomicAdd(&sums[2 * c + 1], b);
  }
}

// row-split per-feature reduce of R x F (F % 256 == 0); grid (F/256, RB).
// fp64 sums of quarter-int lattice values are exact -> atomic order irrelevant.
__global__ void reduce_cols2(const float* __restrict__ x, double* __restrict__ sums,
                             int R, int F, int RS) {
  int f = blockIdx.x * blockDim.x + threadIdx.x;
  int r0 = blockIdx.y * RS, r1 = min(r0 + RS, R);
  double s = 0.0, s2 = 0.0;
  for (int r = r0; r < r1; r++) {
    double v = (double)x[(long)r * F + f];
    s += v; s2 += v * v;
  }
  atomicAdd(&sums[2 * f], s);
  atomicAdd(&sums[2 * f + 1], s2);
}

__global__ void finalize_stats(const double* __restrict__ sums, double2* __restrict__ st,
                               int C, double cnt) {
  int c = blockIdx.x * blockDim.x + threadIdx.x;
  if (c >= C) return;
  double m = sums[2 * c] / cnt;
  double v = sums[2 * c + 1] / cnt - m * m;
  st[c] = make_double2(m, 1.0 / sqrt(v + BN_EPS));
}

// ---------------- ballot-based sign/pack kernels ----------------

__global__ void pack_bits_c1(const float* __restrict__ x, const double2* __restrict__ st,
                             const float* __restrict__ g, const float* __restrict__ b,
                             uint64_t* __restrict__ rows) {
  int wid = blockIdx.x * 4 + (threadIdx.x >> 6);
  int lane = threadIdx.x & 63;
  int n = wid / 192, rem = wid % 192;
  int ci = rem >> 6, y = rem & 63;
  double2 s = st[ci];
  float xv = x[(((long)n * 3 + ci) * 64 + y) * 64 + lane];
  float xn = (float)(((double)xv - s.x) * s.y) * g[ci] + b[ci];
  uint64_t m = __ballot(xn > 0.f);
  if (lane == 0) rows[wid] = m;
}

__global__ void pack_wc1(const float* __restrict__ w, uint32_t* __restrict__ wm) {
  int co = threadIdx.x;
  uint32_t m = 0;
  for (int j = 0; j < 27; j++) m |= (uint32_t)(w[co * 27 + j] > 0.f) << j;
  wm[co] = m;
}

__global__ void pack_cl(const float* __restrict__ acl, const double2* __restrict__ st,
                        const float* __restrict__ g, const float* __restrict__ b,
                        uint64_t* __restrict__ out, int C, long nwords, int lw) {
  long wid = (long)blockIdx.x * 4 + (threadIdx.x >> 6);
  if (wid >= nwords) return;
  int lane = threadIdx.x & 63;
  long row = wid >> lw;
  int w = (int)(wid & ((1 << lw) - 1));
  int c = w * 64 + lane;
  double2 s = st[c];
  float xv = acl[row * C + c];
  float xn = (float)(((double)xv - s.x) * s.y) * g[c] + b[c];
  uint64_t m = __ballot(xn > 0.f);
  if (lane == 0) out[wid] = m;
}

__global__ void pack_wconv(const float* __restrict__ w, uint64_t* __restrict__ out,
                           int CO, int CI, int W) {
  int i = blockIdx.x * blockDim.x + threadIdx.x;
  int total = CO * 9 * W;
  if (i >= total) return;
  int wd = i % W;
  int t = i / W;
  int tap = t % 9, co = t / 9;
  uint64_t bits = 0;
  for (int k = 0; k < 64; k++) {
    int ci = wd * 64 + k;
    bits |= (uint64_t)(w[((long)co * CI + ci) * 9 + tap] > 0.f) << k;
  }
  out[i] = bits;
}

__global__ void pack_nz(const float* __restrict__ x, const double2* __restrict__ st,
                        const float* __restrict__ g, const float* __restrict__ b,
                        uint64_t* __restrict__ out, int R, int F) {
  int Wf = F >> 6;
  long wid = (long)blockIdx.x * 4 + (threadIdx.x >> 6);
  if (wid >= (long)R * Wf) return;
  int lane = threadIdx.x & 63;
  long r = wid / Wf;
  int w = (int)(wid % Wf);
  int f = w * 64 + lane;
  double2 s = st[f];
  double d = (double)x[r * F + f] - s.x;  // exact for lattice values
  float xn = (float)(d * s.y) * g[f] + b[f];
  uint64_t sm = __ballot(xn > 0.f);
  uint64_t nm = __ballot(d != 0.0);
  if (lane == 0) { out[2 * wid] = sm; out[2 * wid + 1] = nm; }
}

__global__ void pack_wfc2(const float* __restrict__ w, uint64_t* __restrict__ out,
                          int O, int F) {
  int Wf = F >> 6;
  long wid = (long)blockIdx.x * 4 + (threadIdx.x >> 6);
  if (wid >= (long)O * Wf) return;
  int lane = threadIdx.x & 63;
  long o = wid / Wf;
  int wd = (int)(wid % Wf);
  uint64_t m = __ballot(w[o * F + wd * 64 + lane] > 0.f);
  if (lane == 0) out[wid] = m;
}

// ---------------- fused conv + maxpool + prelu ----------------

// conv1 via 27-bit xnor-popcount; out channel-last [n][961][128]
__global__ __launch_bounds__(256) void conv1_pool3(const uint64_t* __restrict__ rows,
                                                   const uint32_t* __restrict__ wm,
                                                   const float* __restrict__ cp,
                                                   float* __restrict__ out) {
  __shared__ uint64_t rL[192];
  __shared__ uint32_t wL[128];
  __shared__ uint32_t mL[61 * 4];
  int n = blockIdx.y, chunk = blockIdx.x, t = threadIdx.x;
  if (t < 192) rL[t] = rows[n * 192 + t];
  if (t < 128) wL[t] = wm[t];
  __syncthreads();
  if (t < 244) {
    int pl = t >> 2, quad = t & 3;
    int pos = chunk * 61 + pl;
    if (pos < 961) {
      int py = pos / 31, px = pos - py * 31;
      int cy = 2 * py + (quad >> 1), cx = 2 * px + (quad & 1);
      uint32_t m = 0;
#pragma unroll
      for (int ci = 0; ci < 3; ci++)
#pragma unroll
        for (int ky = 0; ky < 3; ky++)
          m |= (uint32_t)((rL[ci * 64 + cy + ky] >> cx) & 7) << (ci * 9 + ky * 3);
      mL[pl * 4 + quad] = m;
    }
  }
  __syncthreads();
  int co = t & 127, slot = t >> 7;
  float alpha = cp[0];
  uint32_t w = wL[co];
  for (int i = slot; i < 61; i += 2) {
    int pos = chunk * 61 + i;
    if (pos >= 961) break;
    int p0 = __popc(mL[4 * i] ^ w);
    int p1 = __popc(mL[4 * i + 1] ^ w);
    int p2 = __popc(mL[4 * i + 2] ^ w);
    int p3 = __popc(mL[4 * i + 3] ^ w);
    int dot = 27 - 2 * min(min(p0, p1), min(p2, p3));
    float f = (float)dot;
    out[((long)n * 961 + pos) * 128 + co] = dot >= 0 ? f : alpha * f;
  }
}

// half-window load: columns (cx, cx+1), rows cy=0..3, into h[cy][0..2W)
template <int W, int IH>
__device__ __forceinline__ void load_half(uint64_t (&h)[4][2 * W],
                                          const uint64_t* __restrict__ sIn,
                                          int py, int cx) {
#pragma unroll
  for (int cy = 0; cy < 4; cy++) {
    const uint64_t* p = &sIn[((2 * py + cy) * IH + cx) * W];
#pragma unroll
    for (int i = 0; i < 2 * W; i++) h[cy][i] = p[i];
  }
}

// popcounts of the 4 pool quadrants from window halves A(cols 0,1) B(cols 2,3)
template <int W>
__device__ __forceinline__ void conv_quad(const uint64_t (&A)[4][2 * W],
                                          const uint64_t (&B)[4][2 * W],
                                          const uint64_t (&wr)[9 * W],
                                          int& a00, int& a01, int& a10, int& a11) {
  a00 = a01 = a10 = a11 = 0;
#pragma unroll
  for (int cy = 0; cy < 4; cy++) {
#pragma unroll
    for (int dy = 0; dy < 2; dy++) {
      int ky = cy - dy;
      if (ky < 0 || ky > 2) continue;  // compile-time folded
#pragma unroll
      for (int dx = 0; dx < 2; dx++) {
        int acc = 0;
#pragma unroll
        for (int kx = 0; kx < 3; kx++) {
          int col = dx + kx;
#pragma unroll
          for (int wd = 0; wd < W; wd++) {
            uint64_t pv = (col < 2) ? A[cy][col * W + wd] : B[cy][(col - 2) * W + wd];
            acc += __popcll(pv ^ wr[(ky * 3 + kx) * W + wd]);
          }
        }
        if (dy == 0) { if (dx == 0) a00 += acc; else a01 += acc; }
        else         { if (dx == 0) a10 += acc; else a11 += acc; }
      }
    }
  }
}

// sliding-window xnor conv + pool + prelu: one wave per (co-group, py).
// launch_bounds(256,4): 128-VGPR cap so the 9W weight words LIVE in registers
// (bare (256) capped at ~36 VGPR and silently demoted them -> R5 stagnation).
// in [n][IH][IH][W], wt [co][9W], out channel-last [n][PH*PH][CO].
template <int W, int IH, int PH, int CHUNK>
__global__ __launch_bounds__(256, 4) void convp_slide(
    const uint64_t* __restrict__ in, const uint64_t* __restrict__ wt,
    const float* __restrict__ cp, float* __restrict__ out, int CO) {
  __shared__ uint64_t sIn[IH * IH * W];
  int n = blockIdx.y;
  int cg = blockIdx.x / CHUNK, chunk = blockIdx.x % CHUNK;
  int t = threadIdx.x, lane = t & 63, slot = t >> 6;
  const uint64_t* src = in + (long)n * (IH * IH * W);
  for (int i = t; i < IH * IH * W; i += 256) sIn[i] = src[i];
  int co = cg * 64 + lane;
  uint64_t wr[9 * W];
  const uint64_t* wg = wt + (long)co * (9 * W);
#pragma unroll
  for (int i = 0; i < 9 * W; i++) wr[i] = wg[i];
  __syncthreads();
  int py = chunk * 4 + slot;
  if (py >= PH) return;
  float alpha = cp[0];
  const int K = 9 * 64 * W;
  uint64_t hA[4][2 * W], hB[4][2 * W];
  load_half<W, IH>(hA, sIn, py, 0);
#pragma unroll
  for (int px = 0; px < PH; px += 2) {
    load_half<W, IH>(hB, sIn, py, 2 * px + 2);
    {
      int a00, a01, a10, a11;
      conv_quad<W>(hA, hB, wr, a00, a01, a10, a11);
      int dot = K - 2 * min(min(a00, a01), min(a10, a11));
      float f = (float)dot;
      out[((long)n * PH * PH + py * PH + px) * CO + co] = dot >= 0 ? f : alpha * f;
    }
    if (px + 1 < PH) {
      load_half<W, IH>(hA, sIn, py, 2 * px + 4);
      int a00, a01, a10, a11;
      conv_quad<W>(hB, hA, wr, a00, a01, a10, a11);
      int dot = K - 2 * min(min(a00, a01), min(a10, a11));
      float f = (float)dot;
      out[((long)n * PH * PH + py * PH + px + 1) * CO + co] = dot >= 0 ? f : alpha * f;
    }
  }
}

// v3 per-position kernel (kept for conv3, W=4), now with a real register budget.
template <int W, int IH, int PH, int POSCH, bool CL>
__global__ __launch_bounds__(256, 4) void convp_pool3(
    const uint64_t* __restrict__ in, const uint64_t* __restrict__ wt,
    const float* __restrict__ cp, float* __restrict__ out, int CO) {
  __shared__ uint64_t sIn[IH * IH * W];
  int n = blockIdx.y;
  int cg = blockIdx.x / POSCH;
  int chunk = blockIdx.x % POSCH;
  int t = threadIdx.x;
  const uint64_t* src = in + (long)n * (IH * IH * W);
  for (int i = t; i < IH * IH * W; i += 256) sIn[i] = src[i];
  int lane = t & 63;
  int slot = t >> 6;
  int co = cg * 64 + lane;
  uint64_t wr[9 * W];
  const uint64_t* wg = wt + (long)co * (9 * W);
#pragma unroll
  for (int i = 0; i < 9 * W; i++) wr[i] = wg[i];
  __syncthreads();
  float alpha = cp[0];
  for (int pos = chunk * 4 + slot; pos < PH * PH; pos += POSCH * 4) {
    int py = pos / PH, px = pos % PH;
    int a00 = 0, a01 = 0, a10 = 0, a11 = 0;
#pragma unroll
    for (int cy = 0; cy < 4; cy++) {
      uint64_t row[4 * W];
      const uint64_t* rp = &sIn[((2 * py + cy) * IH + 2 * px) * W];
#pragma unroll
      for (int i = 0; i < 4 * W; i++) row[i] = rp[i];
#pragma unroll
      for (int dy = 0; dy < 2; dy++) {
        int ky = cy - dy;
        if (ky < 0 || ky > 2) continue;
#pragma unroll
        for (int dx = 0; dx < 2; dx++) {
          int a = 0;
#pragma unroll
          for (int kx = 0; kx < 3; kx++)
#pragma unroll
            for (int wd = 0; wd < W; wd++)
              a += __popcll(row[(dx + kx) * W + wd] ^ wr[(ky * 3 + kx) * W + wd]);
          if (dy == 0) { if (dx == 0) a00 += a; else a01 += a; }
          else         { if (dx == 0) a10 += a; else a11 += a; }
        }
      }
    }
    int pmin = min(min(a00, a01), min(a10, a11));
    int dot = 9 * 64 * W - 2 * pmin;
    float f = (float)dot;
    long idx = CL ? (((long)n * PH * PH + pos) * CO + co)
                  : (((long)n * CO + co) * PH * PH + pos);
    out[idx] = dot >= 0 ? f : alpha * f;
  }
}

// ---------------- binary fc (with nonzero mask on activations) ----------------

__global__ void fc_bin(const uint64_t* __restrict__ xp, const uint64_t* __restrict__ wp,
                       const float* __restrict__ cp, float* __restrict__ out,
                       int O, int Wf) {
  __shared__ uint64_t xs[288], xz[288];
  int r = blockIdx.y;
  for (int i = threadIdx.x; i < Wf; i += blockDim.x) {
    xs[i] = xp[((long)r * Wf + i) * 2];
    xz[i] = xp[((long)r * Wf + i) * 2 + 1];
  }
  __syncthreads();
  int o = blockIdx.x * blockDim.x + threadIdx.x;
  if (o >= O) return;
  int pc = 0, nzc = 0;
  const uint64_t* wr = wp + (long)o * Wf;
  for (int wd = 0; wd < Wf; wd++) {
    uint64_t nz = xz[wd];
    pc  += __popcll((xs[wd] ^ wr[wd]) & nz);
    nzc += __popcll(nz);
  }
  int dot = nzc - 2 * pc;
  float f = (float)dot;
  float alpha = cp[0];
  out[(long)r * O + o] = dot >= 0 ? f : alpha * f;
}

__global__ void fc_bin_scale(const uint64_t* __restrict__ xp, const uint64_t* __restrict__ wp,
                             const float* __restrict__ cp, const float* __restrict__ scale,
                             float* __restrict__ out, int R, int O, int Wf) {
  int i = blockIdx.x * blockDim.x + threadIdx.x;
  if (i >= R * O) return;
  int o = i % O, r = i / O;
  int pc = 0, nzc = 0;
  for (int wd = 0; wd < Wf; wd++) {
    uint64_t nz = xp[((long)r * Wf + wd) * 2 + 1];
    pc  += __popcll((xp[((long)r * Wf + wd) * 2] ^ wp[(long)o * Wf + wd]) & nz);
    nzc += __popcll(nz);
  }
  int dot = nzc - 2 * pc;
  float f = (float)dot;
  float alpha = cp[0];
  f = dot >= 0 ? f : alpha * f;
  out[i] = f * scale[0];
}

// ---------------- launch ----------------

extern "C" void kernel_launch(void* const* d_in, const int* in_sizes, int n_in,
                              void* d_out, int out_size, void* d_ws, size_t ws_size,
                              hipStream_t stream) {
  const float* x   = (const float*)d_in[0];
  const float* cg0 = (const float*)d_in[1];
  const float* cb0 = (const float*)d_in[2];
  const float* cw0 = (const float*)d_in[3];
  const float* cp0 = (const float*)d_in[4];
  const float* cg1 = (const float*)d_in[5];
  const float* cb1 = (const float*)d_in[6];
  const float* cw1 = (const float*)d_in[7];
  const float* cp1 = (const float*)d_in[8];
  const float* cg2 = (const float*)d_in[9];
  const float* cb2 = (const float*)d_in[10];
  const float* cw2 = (const float*)d_in[11];
  const float* cp2 = (const float*)d_in[12];
  const float* fg0 = (const float*)d_in[13];
  const float* fb0 = (const float*)d_in[14];
  const float* fw0 = (const float*)d_in[15];
  const float* fp0 = (const float*)d_in[16];
  const float* fg1 = (const float*)d_in[17];
  const float* fb1 = (const float*)d_in[18];
  const float* fw1 = (const float*)d_in[19];
  const float* fp1 = (const float*)d_in[20];
  const float* scl = (const float*)d_in[21];

  char* ws = (char*)d_ws;
  size_t off = 0;
  auto alloc = [&](size_t bytes) {
    size_t r = off;
    off += (bytes + 255) & ~(size_t)255;
    return r;
  };
  const int C0_OFF = 0, C1_OFF = 16, C2_OFF = 160, C3_OFF = 448, C4_OFF = 18944;
  const int NCH = 19968;

  double*   sums  = (double*)(ws + alloc((size_t)NCH * 2 * sizeof(double)));
  double2*  stats = (double2*)(ws + alloc((size_t)NCH * sizeof(double2)));
  uint64_t* rows0 = (uint64_t*)(ws + alloc(128L * 3 * 64 * 8));
  uint32_t* wm1   = (uint32_t*)(ws + alloc(128L * 4));
  float*    a1    = (float*)(ws + alloc(128L * 961 * 128 * 4));   // channel-last
  uint64_t* s1p   = (uint64_t*)(ws + alloc(128L * 961 * 2 * 8));
  uint64_t* w1p   = (uint64_t*)(ws + alloc(256L * 9 * 2 * 8));
  float*    a2    = (float*)(ws + alloc(128L * 196 * 256 * 4));   // channel-last
  uint64_t* s2p   = (uint64_t*)(ws + alloc(128L * 196 * 4 * 8));
  uint64_t* w2p   = (uint64_t*)(ws + alloc(512L * 9 * 4 * 8));
  float*    a3    = (float*)(ws + alloc(128L * 512 * 36 * 4));    // channel-major (reshape order)
  uint64_t* s3p   = (uint64_t*)(ws + alloc(128L * 288 * 2 * 8));
  uint64_t* w3p   = (uint64_t*)(ws + alloc(1024L * 288 * 8));
  float*    f1    = (float*)(ws + alloc(128L * 1024 * 4));
  uint64_t* s4p   = (uint64_t*)(ws + alloc(128L * 16 * 2 * 8));
  uint64_t* w4p   = (uint64_t*)(ws + alloc(10L * 16 * 8));

  const int B = 256;

  zero_d<<<dim3(156), B, 0, stream>>>(sums, NCH * 2);  // all atomic regions

  // ---- block 0: BN(x) -> sign-bits -> conv1(popcount) -> pool -> prelu ----
  reduce_plane<<<dim3(3, 128), B, 0, stream>>>(x, sums + 2 * C0_OFF, 3, 4096);
  finalize_stats<<<1, 64, 0, stream>>>(sums + 2 * C0_OFF, stats + C0_OFF, 3, 524288.0);
  pack_bits_c1<<<dim3(6144), B, 0, stream>>>(x, stats + C0_OFF, cg0, cb0, rows0);
  pack_wc1<<<1, 128, 0, stream>>>(cw0, wm1);
  conv1_pool3<<<dim3(16, 128), B, 0, stream>>>(rows0, wm1, cp0, a1);

  // ---- block 1: BN(a1) -> pack -> conv2 -> pool -> prelu ----
  reduce_cl<<<dim3(2, 256), B, 0, stream>>>(a1, sums + 2 * C1_OFF, 128, 123008L);
  finalize_stats<<<1, 128, 0, stream>>>(sums + 2 * C1_OFF, stats + C1_OFF, 128, 123008.0);
  pack_cl<<<dim3(61504), B, 0, stream>>>(a1, stats + C1_OFF, cg1, cb1, s1p, 128, 246016L, 1);
  pack_wconv<<<dim3(18), B, 0, stream>>>(cw1, w1p, 256, 128, 2);
  // 4 co-groups x 4 py-chunks
  convp_slide<2, 31, 14, 4><<<dim3(16, 128), B, 0, stream>>>(s1p, w1p, cp1, a2, 256);

  // ---- block 2: BN(a2) -> pack -> conv3 -> pool -> prelu ----
  reduce_cl<<<dim3(4, 128), B, 0, stream>>>(a2, sums + 2 * C2_OFF, 256, 25088L);
  finalize_stats<<<1, 256, 0, stream>>>(sums + 2 * C2_OFF, stats + C2_OFF, 256, 25088.0);
  pack_cl<<<dim3(25088), B, 0, stream>>>(a2, stats + C2_OFF, cg2, cb2, s2p, 256, 100352L, 2);
  pack_wconv<<<dim3(72), B, 0, stream>>>(cw2, w2p, 512, 256, 4);
  convp_pool3<4, 14, 6, 2, false><<<dim3(16, 128), B, 0, stream>>>(s2p, w2p, cp2, a3, 512);

  // ---- fc 0: BN1d -> sign @ sign(W).T -> prelu ----
  reduce_cols2<<<dim3(72, 8), B, 0, stream>>>(a3, sums + 2 * C3_OFF, 128, 18432, 16);
  finalize_stats<<<dim3(72), B, 0, stream>>>(sums + 2 * C3_OFF, stats + C3_OFF, 18432, 128.0);
  pack_nz<<<dim3(9216), B, 0, stream>>>(a3, stats + C3_OFF, fg0, fb0, s3p, 128, 18432);
  pack_wfc2<<<dim3(73728), B, 0, stream>>>(fw0, w3p, 1024, 18432);
  fc_bin<<<dim3(4, 128), B, 0, stream>>>(s3p, w3p, fp0, f1, 1024, 288);

  // ---- fc 1: BN1d -> sign @ sign(W).T -> prelu -> scale ----
  reduce_cols2<<<dim3(4, 8), B, 0, stream>>>(f1, sums + 2 * C4_OFF, 128, 1024, 16);
  finalize_stats<<<dim3(4), B, 0, stream>>>(sums + 2 * C4_OFF, stats + C4_OFF, 1024, 128.0);
  pack_nz<<<dim3(512), B, 0, stream>>>(f1, stats + C4_OFF, fg1, fb1, s4p, 128, 1024);
  pack_wfc2<<<dim3(40), B, 0, stream>>>(fw1, w4p, 10, 1024);
  fc_bin_scale<<<dim3(5), B, 0, stream>>>(s4p, w4p, fp1, scl, (float*)d_out, 128, 10, 16);
}